// Round 1
// baseline (1413.655 us; speedup 1.0000x reference)
//
#include <hip/hip_runtime.h>

#define B_ 2
#define N_ 1569
#define C_ 768
#define H_ 12
#define D_ 64
#define P_ 196
#define F_ 8
#define S_ 1568
#define QKVLD 2304
#define SCALE 0.125f

// ---------------------------------------------------------------------------
// Generic fp32 GEMM: C[M,Nn] = alpha * A[M,K] @ B[K,Nn(ldb)] (+ bias)
// 128x128 tile, BK=16, 256 threads, 8x8 micro-tile (split 4+4).
// GATHER=1: A row m comes from traj row (m*F + (m%S)/P)  (x_diag gather).
// ---------------------------------------------------------------------------
template<int GATHER>
__global__ __launch_bounds__(256)
void gemm_f32(const float* __restrict__ A, const float* __restrict__ Bm,
              float* __restrict__ Cm, int M, int Nn, int K, int ldb,
              float alpha, const float* __restrict__ bias)
{
    __shared__ float As[16][132];
    __shared__ float Bs[16][132];

    const int tid = threadIdx.x;
    const int m0 = blockIdx.x * 128, n0 = blockIdx.y * 128;
    const int tx = tid & 15, ty = tid >> 4;
    const int ar = tid >> 2, ac4 = tid & 3;
    const int br = tid >> 5, bc4 = tid & 31;

    const float* a0p;
    const float* a1p;
    {
        int m = m0 + ar;       int mm = m  < M ? m  : M - 1;
        int m2 = m0 + ar + 64; int mm2 = m2 < M ? m2 : M - 1;
        if (GATHER) {
            long r0 = (long)mm  * F_ + (mm  % S_) / P_;
            long r1 = (long)mm2 * F_ + (mm2 % S_) / P_;
            a0p = A + r0 * (long)K;
            a1p = A + r1 * (long)K;
        } else {
            a0p = A + (long)mm  * K;
            a1p = A + (long)mm2 * K;
        }
    }
    const float* bp = Bm + (long)br * ldb + n0 + bc4 * 4;

    float4 aR0 = *(const float4*)(a0p + ac4 * 4);
    float4 aR1 = *(const float4*)(a1p + ac4 * 4);
    float4 bR0 = *(const float4*)bp;
    float4 bR1 = *(const float4*)(bp + 8 * (long)ldb);

    float acc[8][8];
#pragma unroll
    for (int i = 0; i < 8; i++)
#pragma unroll
        for (int j = 0; j < 8; j++) acc[i][j] = 0.f;

    const int nk = K >> 4;
    for (int kt = 0; kt < nk; kt++) {
        __syncthreads();
        As[ac4*4+0][ar]    = aR0.x; As[ac4*4+1][ar]    = aR0.y;
        As[ac4*4+2][ar]    = aR0.z; As[ac4*4+3][ar]    = aR0.w;
        As[ac4*4+0][ar+64] = aR1.x; As[ac4*4+1][ar+64] = aR1.y;
        As[ac4*4+2][ar+64] = aR1.z; As[ac4*4+3][ar+64] = aR1.w;
        *(float4*)&Bs[br][bc4*4]     = bR0;
        *(float4*)&Bs[br+8][bc4*4]   = bR1;
        __syncthreads();
        if (kt + 1 < nk) {
            int k0 = (kt + 1) * 16;
            aR0 = *(const float4*)(a0p + k0 + ac4 * 4);
            aR1 = *(const float4*)(a1p + k0 + ac4 * 4);
            bR0 = *(const float4*)(bp + (long)k0 * ldb);
            bR1 = *(const float4*)(bp + (long)(k0 + 8) * ldb);
        }
#pragma unroll
        for (int k = 0; k < 16; k++) {
            float4 a0 = *(const float4*)&As[k][ty*4];
            float4 a1 = *(const float4*)&As[k][64 + ty*4];
            float4 b0 = *(const float4*)&Bs[k][tx*4];
            float4 b1 = *(const float4*)&Bs[k][64 + tx*4];
            float av[8] = {a0.x,a0.y,a0.z,a0.w,a1.x,a1.y,a1.z,a1.w};
            float bv[8] = {b0.x,b0.y,b0.z,b0.w,b1.x,b1.y,b1.z,b1.w};
#pragma unroll
            for (int i = 0; i < 8; i++)
#pragma unroll
                for (int j = 0; j < 8; j++)
                    acc[i][j] = fmaf(av[i], bv[j], acc[i][j]);
        }
    }

#pragma unroll
    for (int ih = 0; ih < 2; ih++)
#pragma unroll
    for (int i = 0; i < 4; i++) {
        int m = m0 + ih * 64 + ty * 4 + i;
        if (m < M) {
#pragma unroll
            for (int jh = 0; jh < 2; jh++) {
                int n = n0 + jh * 64 + tx * 4;
                float4 r;
                r.x = acc[ih*4+i][jh*4+0] * alpha;
                r.y = acc[ih*4+i][jh*4+1] * alpha;
                r.z = acc[ih*4+i][jh*4+2] * alpha;
                r.w = acc[ih*4+i][jh*4+3] * alpha;
                if (bias) {
                    r.x += bias[n+0]; r.y += bias[n+1];
                    r.z += bias[n+2]; r.w += bias[n+3];
                }
                *(float4*)&Cm[(long)m * Nn + n] = r;
            }
        }
    }
}

// ---------------------------------------------------------------------------
// CLS attention: one block per (b,h). q = row 0, keys/values = all N rows.
// Writes row 0 of outcat (B, N_, C).
// ---------------------------------------------------------------------------
__global__ __launch_bounds__(256)
void cls_attn(const float* __restrict__ qkv, float* __restrict__ outcat)
{
    const int bh = blockIdx.x;
    const int b = bh / H_, hh = bh % H_;
    __shared__ float qs[64];
    __shared__ float sc[N_];
    __shared__ float red[256];
    const int t = threadIdx.x;

    const float* qrow = qkv + (long)(b * N_) * QKVLD + hh * 64;
    if (t < 64) qs[t] = qrow[t];
    __syncthreads();

    float lmax = -1e30f;
    for (int n = t; n < N_; n += 256) {
        const float* krow = qkv + (long)(b * N_ + n) * QKVLD + 768 + hh * 64;
        float acc = 0.f;
#pragma unroll
        for (int j4 = 0; j4 < 16; j4++) {
            float4 kv = *(const float4*)(krow + j4 * 4);
            acc = fmaf(kv.x, qs[j4*4+0], acc);
            acc = fmaf(kv.y, qs[j4*4+1], acc);
            acc = fmaf(kv.z, qs[j4*4+2], acc);
            acc = fmaf(kv.w, qs[j4*4+3], acc);
        }
        acc *= SCALE;
        sc[n] = acc;
        lmax = fmaxf(lmax, acc);
    }
    red[t] = lmax;
    __syncthreads();
    for (int s = 128; s > 0; s >>= 1) {
        if (t < s) red[t] = fmaxf(red[t], red[t + s]);
        __syncthreads();
    }
    float m = red[0];
    __syncthreads();

    float lsum = 0.f;
    for (int n = t; n < N_; n += 256) {
        float w = __expf(sc[n] - m);
        sc[n] = w;
        lsum += w;
    }
    red[t] = lsum;
    __syncthreads();
    for (int s = 128; s > 0; s >>= 1) {
        if (t < s) red[t] += red[t + s];
        __syncthreads();
    }
    float rsum = 1.f / red[0];

    const int j = t & 63, part = t >> 6;
    float acc = 0.f;
    for (int n = part; n < N_; n += 4)
        acc = fmaf(sc[n], qkv[(long)(b * N_ + n) * QKVLD + 1536 + hh * 64 + j], acc);
    __syncthreads();
    red[t] = acc;
    __syncthreads();
    if (t < 64) {
        float o = (red[t] + red[64 + t] + red[128 + t] + red[192 + t]) * rsum;
        outcat[(long)(b * N_) * C_ + hh * 64 + t] = o;
    }
}

// ---------------------------------------------------------------------------
// Trajectory attention. Block = (qt, h, b), 512 threads, TQ=32 queries.
// Per frame f: scores(32x196x64) -> softmax over 196 -> PV -> traj[b,s,f,h*64+j].
// LDS ~142KB -> 1 block/CU, 8 waves.
// ---------------------------------------------------------------------------
__global__ __launch_bounds__(512)
void traj_attn(const float* __restrict__ qkv, float* __restrict__ traj)
{
    __shared__ float Qs[32][68];      // natural [q][j], stride 68 (16B-aligned rows)
    __shared__ float Ks[196][68];
    __shared__ float Vs[196][68];
    __shared__ float ws[196][36];     // transposed weights [p][q]
    __shared__ float red[32][16];
    __shared__ float mrow[32];
    __shared__ float srow[32];

    const int t  = threadIdx.x;
    const int qt = blockIdx.x, hh = blockIdx.y, b = blockIdx.z;
    const int s0 = qt * 32;

    // load Q tile (rows 1+s0 .. 1+s0+31), exactly 512 float4s
    {
        int q = t >> 4, j4 = t & 15;
        const float* qrow = qkv + (long)(b * N_ + 1 + s0 + q) * QKVLD + hh * 64;
        *(float4*)&Qs[q][j4 * 4] = *(const float4*)(qrow + j4 * 4);
    }

    const int ty = t >> 6;        // 0..7
    const int tx = t & 63;        // 0..63
    const int q0 = ty * 4;        // 4 queries per thread
    const int k3 = (tx < 4) ? (192 + tx) : 195;   // ragged 4th key (clamped)

    for (int f = 0; f < F_; f++) {
        __syncthreads();   // prev frame PV done with Vs/ws/srow; Q stores done
        // stage K and V for this frame
        for (int idx = t; idx < P_ * 16; idx += 512) {
            int key = idx >> 4, j4 = idx & 15;
            const float* kr = qkv + (long)(b * N_ + 1 + f * P_ + key) * QKVLD
                              + 768 + hh * 64 + j4 * 4;
            *(float4*)&Ks[key][j4 * 4] = *(const float4*)kr;
            *(float4*)&Vs[key][j4 * 4] = *(const float4*)(kr + 768);
        }
        __syncthreads();

        // scores: 4 queries x 4 key-sets per thread
        float acc[4][4];
#pragma unroll
        for (int i = 0; i < 4; i++)
#pragma unroll
            for (int qi = 0; qi < 4; qi++) acc[i][qi] = 0.f;

        for (int j4 = 0; j4 < 16; j4++) {
            float4 qv0 = *(const float4*)&Qs[q0 + 0][j4 * 4];
            float4 qv1 = *(const float4*)&Qs[q0 + 1][j4 * 4];
            float4 qv2 = *(const float4*)&Qs[q0 + 2][j4 * 4];
            float4 qv3 = *(const float4*)&Qs[q0 + 3][j4 * 4];
            float4 kv0 = *(const float4*)&Ks[tx      ][j4 * 4];
            float4 kv1 = *(const float4*)&Ks[tx +  64][j4 * 4];
            float4 kv2 = *(const float4*)&Ks[tx + 128][j4 * 4];
            float4 kv3 = *(const float4*)&Ks[k3      ][j4 * 4];
#define DOT4(K_, Q_, D_) \
            D_ = fmaf(K_.x, Q_.x, D_); D_ = fmaf(K_.y, Q_.y, D_); \
            D_ = fmaf(K_.z, Q_.z, D_); D_ = fmaf(K_.w, Q_.w, D_);
            DOT4(kv0, qv0, acc[0][0]) DOT4(kv0, qv1, acc[0][1])
            DOT4(kv0, qv2, acc[0][2]) DOT4(kv0, qv3, acc[0][3])
            DOT4(kv1, qv0, acc[1][0]) DOT4(kv1, qv1, acc[1][1])
            DOT4(kv1, qv2, acc[1][2]) DOT4(kv1, qv3, acc[1][3])
            DOT4(kv2, qv0, acc[2][0]) DOT4(kv2, qv1, acc[2][1])
            DOT4(kv2, qv2, acc[2][2]) DOT4(kv2, qv3, acc[2][3])
            DOT4(kv3, qv0, acc[3][0]) DOT4(kv3, qv1, acc[3][1])
            DOT4(kv3, qv2, acc[3][2]) DOT4(kv3, qv3, acc[3][3])
#undef DOT4
        }
#pragma unroll
        for (int qi = 0; qi < 4; qi++) {
            ws[tx      ][q0 + qi] = acc[0][qi];
            ws[tx +  64][q0 + qi] = acc[1][qi];
            ws[tx + 128][q0 + qi] = acc[2][qi];
            if (tx < 4) ws[192 + tx][q0 + qi] = acc[3][qi];
        }
        __syncthreads();

        // softmax over p (raw scores; scale folded into exp)
        {
            int q = t >> 4, c = t & 15;
            float m = -1e30f;
            for (int p = c; p < P_; p += 16) m = fmaxf(m, ws[p][q]);
            red[q][c] = m;
            __syncthreads();
            if (t < 32) {
                float mm = red[t][0];
#pragma unroll
                for (int i = 1; i < 16; i++) mm = fmaxf(mm, red[t][i]);
                mrow[t] = mm;
            }
            __syncthreads();
            float mm = mrow[q];
            float sum = 0.f;
            for (int p = c; p < P_; p += 16) {
                float w = __expf((ws[p][q] - mm) * SCALE);
                ws[p][q] = w;
                sum += w;
            }
            red[q][c] = sum;
            __syncthreads();
            if (t < 32) {
                float ss = 0.f;
#pragma unroll
                for (int i = 0; i < 16; i++) ss += red[t][i];
                srow[t] = 1.f / ss;
            }
            __syncthreads();
        }

        // PV: out[q0..q0+3][tx] = sum_p ws[p][q] * Vs[p][tx]
        float a0 = 0.f, a1 = 0.f, a2 = 0.f, a3 = 0.f;
        for (int p = 0; p < P_; p++) {
            float4 w4 = *(const float4*)&ws[p][q0];
            float vv = Vs[p][tx];
            a0 = fmaf(w4.x, vv, a0);
            a1 = fmaf(w4.y, vv, a1);
            a2 = fmaf(w4.z, vv, a2);
            a3 = fmaf(w4.w, vv, a3);
        }
        {
            long base = ((long)((b * S_ + s0 + q0) * F_ + f)) * C_ + hh * 64 + tx;
            traj[base              ] = a0 * srow[q0 + 0];
            traj[base + (long)F_*C_] = a1 * srow[q0 + 1];
            traj[base + 2L*F_*C_   ] = a2 * srow[q0 + 2];
            traj[base + 3L*F_*C_   ] = a3 * srow[q0 + 3];
        }
    }
}

// ---------------------------------------------------------------------------
// Second attention over F=8 + weighted traj sum. Block = (b,s).
// Writes attn -> d_out tail, out rows 1..S of outcat.
// ---------------------------------------------------------------------------
__global__ __launch_bounds__(256)
void attn2_kernel(const float* __restrict__ q2, const float* __restrict__ k2,
                  const float* __restrict__ traj, float* __restrict__ outcat,
                  float* __restrict__ attn_out)
{
    const int bs = blockIdx.x;
    const int b = bs / S_, s = bs % S_;
    __shared__ float qs[768];
    __shared__ float ks[8][768];
    __shared__ float logit[12][8];
    __shared__ float wsm[12][8];
    const int t = threadIdx.x;

    const float* qrow = q2 + (long)bs * 768;
    for (int c = t; c < 768; c += 256) qs[c] = qrow[c];
    const float* krow = k2 + (long)bs * 8 * 768;
    for (int idx = t; idx < 8 * 768; idx += 256)
        ks[idx / 768][idx % 768] = krow[idx];
    __syncthreads();

    if (t < 96) {
        int hh = t >> 3, f = t & 7;
        float acc = 0.f;
#pragma unroll 8
        for (int j = 0; j < 64; j++)
            acc = fmaf(qs[hh * 64 + j], ks[f][hh * 64 + j], acc);
        logit[hh][f] = acc;
    }
    __syncthreads();
    if (t < 12) {
        float m = logit[t][0];
#pragma unroll
        for (int f = 1; f < 8; f++) m = fmaxf(m, logit[t][f]);
        float w[8], sum = 0.f;
#pragma unroll
        for (int f = 0; f < 8; f++) { w[f] = __expf(logit[t][f] - m); sum += w[f]; }
        float r = 1.f / sum;
#pragma unroll
        for (int f = 0; f < 8; f++) wsm[t][f] = w[f] * r;
    }
    __syncthreads();
    if (t < 96) {
        int hh = t >> 3, f = t & 7;
        attn_out[((long)(b * H_ + hh) * S_ + s) * 8 + f] = wsm[hh][f];
    }
    const float* trow = traj + (long)bs * 8 * 768;
    float* orow = outcat + ((long)(b * N_) + 1 + s) * 768;
    for (int c = t; c < 768; c += 256) {
        int hh = c >> 6;
        float acc = 0.f;
#pragma unroll
        for (int f = 0; f < 8; f++)
            acc = fmaf(wsm[hh][f], trow[f * 768 + c], acc);
        orow[c] = acc;
    }
}

// ---------------------------------------------------------------------------
extern "C" void kernel_launch(void* const* d_in, const int* in_sizes, int n_in,
                              void* d_out, int out_size, void* d_ws, size_t ws_size,
                              hipStream_t stream)
{
    (void)in_sizes; (void)n_in; (void)out_size; (void)ws_size;
    const float* x     = (const float*)d_in[0];
    const float* Wqkv  = (const float*)d_in[1];
    const float* Wpq   = (const float*)d_in[2];
    const float* Wpkv  = (const float*)d_in[3];
    const float* Wproj = (const float*)d_in[4];
    const float* bproj = (const float*)d_in[5];
    float* out = (float*)d_out;

    float* ws     = (float*)d_ws;
    float* qkv    = ws;                                    // 3138*2304
    float* traj   = qkv  + (size_t)3138 * 2304;            // 25088*768
    float* q2     = traj + (size_t)25088 * 768;            // 3136*768
    float* k2     = q2   + (size_t)3136 * 768;             // 25088*768
    float* outcat = k2   + (size_t)25088 * 768;            // 3138*768
    float* attn_out = out + (size_t)3138 * 768;

    // 1. qkv = x @ W_qkv
    gemm_f32<0><<<dim3(25, 18), 256, 0, stream>>>(x, Wqkv, qkv, 3138, 2304, 768, 2304, 1.f, nullptr);
    // 2. CLS attention -> outcat row 0
    cls_attn<<<24, 256, 0, stream>>>(qkv, outcat);
    // 3. trajectory attention -> traj (B,S,F,C)
    traj_attn<<<dim3(49, 12, 2), 512, 0, stream>>>(qkv, traj);
    // 4. q2 = (x_diag @ W_pq) * scale  (gathered rows of traj)
    gemm_f32<1><<<dim3(25, 6), 256, 0, stream>>>(traj, Wpq, q2, 3136, 768, 768, 768, SCALE, nullptr);
    // 5. k2 = traj @ W_pkv[:, :768]   (v2 half of reference is dead code)
    gemm_f32<0><<<dim3(196, 6), 256, 0, stream>>>(traj, Wpkv, k2, 25088, 768, 768, 1536, 1.f, nullptr);
    // 6. F-attention + weighted traj sum -> outcat rows 1.., attn -> d_out tail
    attn2_kernel<<<3136, 256, 0, stream>>>(q2, k2, traj, outcat, attn_out);
    // 7. out = outcat @ W_proj + b_proj
    gemm_f32<0><<<dim3(25, 6), 256, 0, stream>>>(outcat, Wproj, out, 3138, 768, 768, 768, 1.f, bproj);
}

// Round 2
// 881.796 us; speedup vs baseline: 1.6032x; 1.6032x over previous
//
#include <hip/hip_runtime.h>

#define B_ 2
#define N_ 1569
#define C_ 768
#define H_ 12
#define D_ 64
#define P_ 196
#define F_ 8
#define S_ 1568
#define QKVLD 2304
#define SCALE 0.125f

typedef unsigned short ushort_t;
using short8 = __attribute__((ext_vector_type(8))) short;
using f32x4  = __attribute__((ext_vector_type(4))) float;

__device__ __forceinline__ ushort_t f2bf(float x) {
    unsigned u = __float_as_uint(x);
    u += 0x7fffu + ((u >> 16) & 1);       // RNE
    return (ushort_t)(u >> 16);
}
__device__ __forceinline__ float bf2f(ushort_t h) {
    return __uint_as_float((unsigned)h << 16);
}

// ---------------------------------------------------------------------------
// fp32 -> bf16 elementwise convert (n4 = n/4 float4 groups)
// ---------------------------------------------------------------------------
__global__ __launch_bounds__(256)
void cvt_f32_bf16(const float* __restrict__ s, ushort_t* __restrict__ d, int n4)
{
    int i = blockIdx.x * 256 + threadIdx.x;
    if (i < n4) {
        float4 v = ((const float4*)s)[i];
        unsigned lo = f2bf(v.x) | ((unsigned)f2bf(v.y) << 16);
        unsigned hi = f2bf(v.z) | ((unsigned)f2bf(v.w) << 16);
        uint2 o; o.x = lo; o.y = hi;
        ((uint2*)d)[i] = o;
    }
}

// ---------------------------------------------------------------------------
// Transpose+convert: src (K x ldsrc fp32), take cols [0, gridDim.x*32),
// write dst (N x K bf16). Grid (N/32, K/32), 256 threads.
// ---------------------------------------------------------------------------
__global__ __launch_bounds__(256)
void transpose_cvt(const float* __restrict__ src, ushort_t* __restrict__ dst,
                   int K, int ldsrc)
{
    __shared__ float tle[32][33];
    const int n0 = blockIdx.x * 32, k0 = blockIdx.y * 32;
    const int tx = threadIdx.x & 31, ty = threadIdx.x >> 5;  // ty 0..7
#pragma unroll
    for (int j = 0; j < 4; j++)
        tle[ty + 8 * j][tx] = src[(long)(k0 + ty + 8 * j) * ldsrc + n0 + tx];
    __syncthreads();
#pragma unroll
    for (int j = 0; j < 4; j++)
        dst[(long)(n0 + ty + 8 * j) * K + k0 + tx] = f2bf(tle[tx][ty + 8 * j]);
}

// ---------------------------------------------------------------------------
// bf16 MFMA GEMM: C[M,Nn] = alpha * A[M,K] @ Bt[Nn,K]^T (+ bias)
// A row-major bf16, Bt row-major bf16 (pre-transposed weights).
// 128x128 tile, BK=32, 256 threads = 4 waves, each wave 64x64 via 4x4 of
// 16x16x32 MFMA. GATHER: A row m -> m*F + (m%S)/P (x_diag gather on traj).
// OUTBF: write bf16 instead of fp32.
// ---------------------------------------------------------------------------
template<int GATHER, int OUTBF>
__global__ __launch_bounds__(256)
void gemm_bf16(const ushort_t* __restrict__ A, const ushort_t* __restrict__ Bt,
               void* __restrict__ Cv, int M, int Nn, int K,
               float alpha, const float* __restrict__ bias)
{
    __shared__ ushort_t As[128][32];
    __shared__ ushort_t Bs[128][32];

    const int tid = threadIdx.x;
    const int m0 = blockIdx.x * 128, n0 = blockIdx.y * 128;
    const int wave = tid >> 6, lane = tid & 63;
    const int wm = (wave & 1) * 64, wn = (wave >> 1) * 64;
    const int lrow = lane & 15, quad = lane >> 4;

    // staging: thread covers rows srow and srow+64, 16B segment sseg
    const int srow = tid >> 2, sseg = tid & 3;
    int ma0 = m0 + srow;      if (ma0 >= M) ma0 = M - 1;
    int ma1 = m0 + 64 + srow; if (ma1 >= M) ma1 = M - 1;
    long ra0, ra1;
    if (GATHER) {
        ra0 = (long)ma0 * F_ + (ma0 % S_) / P_;
        ra1 = (long)ma1 * F_ + (ma1 % S_) / P_;
    } else { ra0 = ma0; ra1 = ma1; }
    const ushort_t* ap0 = A + ra0 * K + sseg * 8;
    const ushort_t* ap1 = A + ra1 * K + sseg * 8;
    const ushort_t* bp0 = Bt + (long)(n0 + srow) * K + sseg * 8;
    const ushort_t* bp1 = Bt + (long)(n0 + 64 + srow) * K + sseg * 8;

    f32x4 acc[4][4];
#pragma unroll
    for (int i = 0; i < 4; i++)
#pragma unroll
        for (int j = 0; j < 4; j++) acc[i][j] = (f32x4){0.f, 0.f, 0.f, 0.f};

    uint4 aV0 = *(const uint4*)ap0;
    uint4 aV1 = *(const uint4*)ap1;
    uint4 bV0 = *(const uint4*)bp0;
    uint4 bV1 = *(const uint4*)bp1;

    const int nk = K >> 5;
    for (int kt = 0; kt < nk; kt++) {
        __syncthreads();
        *(uint4*)&As[srow][sseg * 8]      = aV0;
        *(uint4*)&As[64 + srow][sseg * 8] = aV1;
        *(uint4*)&Bs[srow][sseg * 8]      = bV0;
        *(uint4*)&Bs[64 + srow][sseg * 8] = bV1;
        __syncthreads();
        if (kt + 1 < nk) {
            int k0 = (kt + 1) * 32;
            aV0 = *(const uint4*)(ap0 + k0);
            aV1 = *(const uint4*)(ap1 + k0);
            bV0 = *(const uint4*)(bp0 + k0);
            bV1 = *(const uint4*)(bp1 + k0);
        }
        short8 af[4], bf[4];
#pragma unroll
        for (int mt = 0; mt < 4; mt++)
            af[mt] = *(const short8*)&As[wm + mt * 16 + lrow][quad * 8];
#pragma unroll
        for (int nt = 0; nt < 4; nt++)
            bf[nt] = *(const short8*)&Bs[wn + nt * 16 + lrow][quad * 8];
#pragma unroll
        for (int mt = 0; mt < 4; mt++)
#pragma unroll
            for (int nt = 0; nt < 4; nt++)
                acc[mt][nt] = __builtin_amdgcn_mfma_f32_16x16x32_bf16(
                    af[mt], bf[nt], acc[mt][nt], 0, 0, 0);
    }

    // C/D layout: col = lane&15, row = quad*4 + reg
#pragma unroll
    for (int mt = 0; mt < 4; mt++) {
#pragma unroll
        for (int nt = 0; nt < 4; nt++) {
            int row = m0 + wm + mt * 16 + quad * 4;
            int col = n0 + wn + nt * 16 + lrow;
            float bv = bias ? bias[col] : 0.f;
#pragma unroll
            for (int r = 0; r < 4; r++) {
                if (row + r < M) {
                    float v = acc[mt][nt][r] * alpha + bv;
                    if (OUTBF)
                        ((ushort_t*)Cv)[(long)(row + r) * Nn + col] = f2bf(v);
                    else
                        ((float*)Cv)[(long)(row + r) * Nn + col] = v;
                }
            }
        }
    }
}

// ---------------------------------------------------------------------------
// CLS attention: one block per (b,h). q = row 0, keys/values = all N rows.
// ---------------------------------------------------------------------------
__global__ __launch_bounds__(256)
void cls_attn(const float* __restrict__ qkv, float* __restrict__ outcat)
{
    const int bh = blockIdx.x;
    const int b = bh / H_, hh = bh % H_;
    __shared__ float qs[64];
    __shared__ float sc[N_];
    __shared__ float red[256];
    const int t = threadIdx.x;

    const float* qrow = qkv + (long)(b * N_) * QKVLD + hh * 64;
    if (t < 64) qs[t] = qrow[t];
    __syncthreads();

    float lmax = -1e30f;
    for (int n = t; n < N_; n += 256) {
        const float* krow = qkv + (long)(b * N_ + n) * QKVLD + 768 + hh * 64;
        float acc = 0.f;
#pragma unroll
        for (int j4 = 0; j4 < 16; j4++) {
            float4 kv = *(const float4*)(krow + j4 * 4);
            acc = fmaf(kv.x, qs[j4*4+0], acc);
            acc = fmaf(kv.y, qs[j4*4+1], acc);
            acc = fmaf(kv.z, qs[j4*4+2], acc);
            acc = fmaf(kv.w, qs[j4*4+3], acc);
        }
        acc *= SCALE;
        sc[n] = acc;
        lmax = fmaxf(lmax, acc);
    }
    red[t] = lmax;
    __syncthreads();
    for (int s = 128; s > 0; s >>= 1) {
        if (t < s) red[t] = fmaxf(red[t], red[t + s]);
        __syncthreads();
    }
    float m = red[0];
    __syncthreads();

    float lsum = 0.f;
    for (int n = t; n < N_; n += 256) {
        float w = __expf(sc[n] - m);
        sc[n] = w;
        lsum += w;
    }
    red[t] = lsum;
    __syncthreads();
    for (int s = 128; s > 0; s >>= 1) {
        if (t < s) red[t] += red[t + s];
        __syncthreads();
    }
    float rsum = 1.f / red[0];

    const int j = t & 63, part = t >> 6;
    float acc = 0.f;
    for (int n = part; n < N_; n += 4)
        acc = fmaf(sc[n], qkv[(long)(b * N_ + n) * QKVLD + 1536 + hh * 64 + j], acc);
    __syncthreads();
    red[t] = acc;
    __syncthreads();
    if (t < 64) {
        float o = (red[t] + red[64 + t] + red[128 + t] + red[192 + t]) * rsum;
        outcat[(long)(b * N_) * C_ + hh * 64 + t] = o;
    }
}

// ---------------------------------------------------------------------------
// Trajectory attention (fp32 compute, bf16 output). Block = (qt, h, b).
// ---------------------------------------------------------------------------
__global__ __launch_bounds__(512)
void traj_attn(const float* __restrict__ qkv, ushort_t* __restrict__ traj)
{
    __shared__ float Qs[32][68];
    __shared__ float Ks[196][68];
    __shared__ float Vs[196][68];
    __shared__ float ws[196][36];
    __shared__ float red[32][16];
    __shared__ float mrow[32];
    __shared__ float srow_[32];

    const int t  = threadIdx.x;
    const int qt = blockIdx.x, hh = blockIdx.y, b = blockIdx.z;
    const int s0 = qt * 32;

    {
        int q = t >> 4, j4 = t & 15;
        const float* qrow = qkv + (long)(b * N_ + 1 + s0 + q) * QKVLD + hh * 64;
        *(float4*)&Qs[q][j4 * 4] = *(const float4*)(qrow + j4 * 4);
    }

    const int ty = t >> 6;
    const int tx = t & 63;
    const int q0 = ty * 4;
    const int k3 = (tx < 4) ? (192 + tx) : 195;

    for (int f = 0; f < F_; f++) {
        __syncthreads();
        for (int idx = t; idx < P_ * 16; idx += 512) {
            int key = idx >> 4, j4 = idx & 15;
            const float* kr = qkv + (long)(b * N_ + 1 + f * P_ + key) * QKVLD
                              + 768 + hh * 64 + j4 * 4;
            *(float4*)&Ks[key][j4 * 4] = *(const float4*)kr;
            *(float4*)&Vs[key][j4 * 4] = *(const float4*)(kr + 768);
        }
        __syncthreads();

        float acc[4][4];
#pragma unroll
        for (int i = 0; i < 4; i++)
#pragma unroll
            for (int qi = 0; qi < 4; qi++) acc[i][qi] = 0.f;

        for (int j4 = 0; j4 < 16; j4++) {
            float4 qv0 = *(const float4*)&Qs[q0 + 0][j4 * 4];
            float4 qv1 = *(const float4*)&Qs[q0 + 1][j4 * 4];
            float4 qv2 = *(const float4*)&Qs[q0 + 2][j4 * 4];
            float4 qv3 = *(const float4*)&Qs[q0 + 3][j4 * 4];
            float4 kv0 = *(const float4*)&Ks[tx      ][j4 * 4];
            float4 kv1 = *(const float4*)&Ks[tx +  64][j4 * 4];
            float4 kv2 = *(const float4*)&Ks[tx + 128][j4 * 4];
            float4 kv3 = *(const float4*)&Ks[k3      ][j4 * 4];
#define DOT4(K_, Q_, D_) \
            D_ = fmaf(K_.x, Q_.x, D_); D_ = fmaf(K_.y, Q_.y, D_); \
            D_ = fmaf(K_.z, Q_.z, D_); D_ = fmaf(K_.w, Q_.w, D_);
            DOT4(kv0, qv0, acc[0][0]) DOT4(kv0, qv1, acc[0][1])
            DOT4(kv0, qv2, acc[0][2]) DOT4(kv0, qv3, acc[0][3])
            DOT4(kv1, qv0, acc[1][0]) DOT4(kv1, qv1, acc[1][1])
            DOT4(kv1, qv2, acc[1][2]) DOT4(kv1, qv3, acc[1][3])
            DOT4(kv2, qv0, acc[2][0]) DOT4(kv2, qv1, acc[2][1])
            DOT4(kv2, qv2, acc[2][2]) DOT4(kv2, qv3, acc[2][3])
            DOT4(kv3, qv0, acc[3][0]) DOT4(kv3, qv1, acc[3][1])
            DOT4(kv3, qv2, acc[3][2]) DOT4(kv3, qv3, acc[3][3])
#undef DOT4
        }
#pragma unroll
        for (int qi = 0; qi < 4; qi++) {
            ws[tx      ][q0 + qi] = acc[0][qi];
            ws[tx +  64][q0 + qi] = acc[1][qi];
            ws[tx + 128][q0 + qi] = acc[2][qi];
            if (tx < 4) ws[192 + tx][q0 + qi] = acc[3][qi];
        }
        __syncthreads();

        {
            int q = t >> 4, c = t & 15;
            float m = -1e30f;
            for (int p = c; p < P_; p += 16) m = fmaxf(m, ws[p][q]);
            red[q][c] = m;
            __syncthreads();
            if (t < 32) {
                float mm = red[t][0];
#pragma unroll
                for (int i = 1; i < 16; i++) mm = fmaxf(mm, red[t][i]);
                mrow[t] = mm;
            }
            __syncthreads();
            float mm = mrow[q];
            float sum = 0.f;
            for (int p = c; p < P_; p += 16) {
                float w = __expf((ws[p][q] - mm) * SCALE);
                ws[p][q] = w;
                sum += w;
            }
            red[q][c] = sum;
            __syncthreads();
            if (t < 32) {
                float ss = 0.f;
#pragma unroll
                for (int i = 0; i < 16; i++) ss += red[t][i];
                srow_[t] = 1.f / ss;
            }
            __syncthreads();
        }

        float a0 = 0.f, a1 = 0.f, a2 = 0.f, a3 = 0.f;
        for (int p = 0; p < P_; p++) {
            float4 w4 = *(const float4*)&ws[p][q0];
            float vv = Vs[p][tx];
            a0 = fmaf(w4.x, vv, a0);
            a1 = fmaf(w4.y, vv, a1);
            a2 = fmaf(w4.z, vv, a2);
            a3 = fmaf(w4.w, vv, a3);
        }
        {
            long base = ((long)((b * S_ + s0 + q0) * F_ + f)) * C_ + hh * 64 + tx;
            traj[base              ] = f2bf(a0 * srow_[q0 + 0]);
            traj[base + (long)F_*C_] = f2bf(a1 * srow_[q0 + 1]);
            traj[base + 2L*F_*C_   ] = f2bf(a2 * srow_[q0 + 2]);
            traj[base + 3L*F_*C_   ] = f2bf(a3 * srow_[q0 + 3]);
        }
    }
}

// ---------------------------------------------------------------------------
// Second attention over F=8 + weighted traj sum. k2/traj are bf16.
// ---------------------------------------------------------------------------
__global__ __launch_bounds__(256)
void attn2_kernel(const float* __restrict__ q2, const ushort_t* __restrict__ k2,
                  const ushort_t* __restrict__ traj, float* __restrict__ outcat,
                  float* __restrict__ attn_out)
{
    const int bs = blockIdx.x;
    const int b = bs / S_, s = bs % S_;
    __shared__ float qs[768];
    __shared__ float ks[8][768];
    __shared__ float logit[12][8];
    __shared__ float wsm[12][8];
    const int t = threadIdx.x;

    const float* qrow = q2 + (long)bs * 768;
    for (int c = t; c < 768; c += 256) qs[c] = qrow[c];
    const ushort_t* krow = k2 + (long)bs * 8 * 768;
    for (int idx = t; idx < 8 * 768; idx += 256)
        ks[idx / 768][idx % 768] = bf2f(krow[idx]);
    __syncthreads();

    if (t < 96) {
        int hh = t >> 3, f = t & 7;
        float acc = 0.f;
#pragma unroll 8
        for (int j = 0; j < 64; j++)
            acc = fmaf(qs[hh * 64 + j], ks[f][hh * 64 + j], acc);
        logit[hh][f] = acc;
    }
    __syncthreads();
    if (t < 12) {
        float m = logit[t][0];
#pragma unroll
        for (int f = 1; f < 8; f++) m = fmaxf(m, logit[t][f]);
        float w[8], sum = 0.f;
#pragma unroll
        for (int f = 0; f < 8; f++) { w[f] = __expf(logit[t][f] - m); sum += w[f]; }
        float r = 1.f / sum;
#pragma unroll
        for (int f = 0; f < 8; f++) wsm[t][f] = w[f] * r;
    }
    __syncthreads();
    if (t < 96) {
        int hh = t >> 3, f = t & 7;
        attn_out[((long)(b * H_ + hh) * S_ + s) * 8 + f] = wsm[hh][f];
    }
    const ushort_t* trow = traj + (long)bs * 8 * 768;
    float* orow = outcat + ((long)(b * N_) + 1 + s) * 768;
    for (int c = t; c < 768; c += 256) {
        int hh = c >> 6;
        float acc = 0.f;
#pragma unroll
        for (int f = 0; f < 8; f++)
            acc = fmaf(wsm[hh][f], bf2f(trow[f * 768 + c]), acc);
        orow[c] = acc;
    }
}

// ---------------------------------------------------------------------------
extern "C" void kernel_launch(void* const* d_in, const int* in_sizes, int n_in,
                              void* d_out, int out_size, void* d_ws, size_t ws_size,
                              hipStream_t stream)
{
    (void)in_sizes; (void)n_in; (void)out_size; (void)ws_size;
    const float* x     = (const float*)d_in[0];
    const float* Wqkv  = (const float*)d_in[1];
    const float* Wpq   = (const float*)d_in[2];
    const float* Wpkv  = (const float*)d_in[3];
    const float* Wproj = (const float*)d_in[4];
    const float* bproj = (const float*)d_in[5];
    float* out = (float*)d_out;

    char* p = (char*)d_ws;
    float*    qkv       = (float*)p;     p += (size_t)7229952 * 4;   // 3138*2304 f32
    ushort_t* traj_bf   = (ushort_t*)p;  p += (size_t)19267584 * 2;  // 25088*768 bf16
    float*    q2        = (float*)p;     p += (size_t)2408448 * 4;   // 3136*768 f32
    ushort_t* k2_bf     = (ushort_t*)p;  p += (size_t)19267584 * 2;  // 25088*768 bf16
    float*    outcat    = (float*)p;     p += (size_t)2409984 * 4;   // 3138*768 f32
    ushort_t* outcat_bf = (ushort_t*)p;  p += (size_t)2409984 * 2;
    ushort_t* x_bf      = (ushort_t*)p;  p += (size_t)2409984 * 2;
    ushort_t* Wqkv_t    = (ushort_t*)p;  p += (size_t)1769472 * 2;   // 2304*768
    ushort_t* Wpq_t     = (ushort_t*)p;  p += (size_t)589824 * 2;    // 768*768
    ushort_t* Wpkv_t    = (ushort_t*)p;  p += (size_t)589824 * 2;    // 768*768 (k-half)
    ushort_t* Wproj_t   = (ushort_t*)p;  p += (size_t)589824 * 2;
    float* attn_out = out + (size_t)3138 * 768;

    // input conversions
    cvt_f32_bf16<<<2354, 256, 0, stream>>>(x, x_bf, 602496);
    transpose_cvt<<<dim3(72, 24), 256, 0, stream>>>(Wqkv,  Wqkv_t,  768, 2304);
    transpose_cvt<<<dim3(24, 24), 256, 0, stream>>>(Wpq,   Wpq_t,   768, 768);
    transpose_cvt<<<dim3(24, 24), 256, 0, stream>>>(Wpkv,  Wpkv_t,  768, 1536);
    transpose_cvt<<<dim3(24, 24), 256, 0, stream>>>(Wproj, Wproj_t, 768, 768);

    // 1. qkv = x @ W_qkv  (fp32 out)
    gemm_bf16<0, 0><<<dim3(25, 18), 256, 0, stream>>>(x_bf, Wqkv_t, qkv, 3138, 2304, 768, 1.f, nullptr);
    // 2. CLS attention -> outcat row 0
    cls_attn<<<24, 256, 0, stream>>>(qkv, outcat);
    // 3. trajectory attention -> traj_bf (B,S,F,C) bf16
    traj_attn<<<dim3(49, 12, 2), 512, 0, stream>>>(qkv, traj_bf);
    // 4. q2 = (x_diag @ W_pq) * scale  (gathered rows of traj_bf)
    gemm_bf16<1, 0><<<dim3(25, 6), 256, 0, stream>>>(traj_bf, Wpq_t, q2, 3136, 768, 768, SCALE, nullptr);
    // 5. k2 = traj @ W_pkv[:, :768]  (v2 half is dead code) -> bf16
    gemm_bf16<0, 1><<<dim3(196, 6), 256, 0, stream>>>(traj_bf, Wpkv_t, k2_bf, 25088, 768, 768, 1.f, nullptr);
    // 6. F-attention + weighted traj sum
    attn2_kernel<<<3136, 256, 0, stream>>>(q2, k2_bf, traj_bf, outcat, attn_out);
    // 7. out = outcat @ W_proj + b_proj
    cvt_f32_bf16<<<2354, 256, 0, stream>>>(outcat, outcat_bf, 602496);
    gemm_bf16<0, 0><<<dim3(25, 6), 256, 0, stream>>>(outcat_bf, Wproj_t, out, 3138, 768, 768, 1.f, bproj);
}

// Round 3
// 501.203 us; speedup vs baseline: 2.8205x; 1.7594x over previous
//
#include <hip/hip_runtime.h>

#define B_ 2
#define N_ 1569
#define C_ 768
#define H_ 12
#define D_ 64
#define P_ 196
#define F_ 8
#define S_ 1568
#define QKVLD 2304
#define SCALE 0.125f

typedef unsigned short ushort_t;
using short8 = __attribute__((ext_vector_type(8))) short;
using f32x4  = __attribute__((ext_vector_type(4))) float;

__device__ __forceinline__ ushort_t f2bf(float x) {
    unsigned u = __float_as_uint(x);
    u += 0x7fffu + ((u >> 16) & 1);       // RNE
    return (ushort_t)(u >> 16);
}
__device__ __forceinline__ float bf2f(ushort_t h) {
    return __uint_as_float((unsigned)h << 16);
}
__device__ __forceinline__ uint2 pack4(float a, float b, float c, float d) {
    uint2 o;
    o.x = f2bf(a) | ((unsigned)f2bf(b) << 16);
    o.y = f2bf(c) | ((unsigned)f2bf(d) << 16);
    return o;
}

// ---------------------------------------------------------------------------
// fp32 -> bf16 elementwise convert (n4 = n/4 float4 groups)
// ---------------------------------------------------------------------------
__global__ __launch_bounds__(256)
void cvt_f32_bf16(const float* __restrict__ s, ushort_t* __restrict__ d, int n4)
{
    int i = blockIdx.x * 256 + threadIdx.x;
    if (i < n4) {
        float4 v = ((const float4*)s)[i];
        ((uint2*)d)[i] = pack4(v.x, v.y, v.z, v.w);
    }
}

// ---------------------------------------------------------------------------
// Transpose+convert weights: src (K x ldsrc fp32) -> dst (N x K bf16)
// ---------------------------------------------------------------------------
__global__ __launch_bounds__(256)
void transpose_cvt(const float* __restrict__ src, ushort_t* __restrict__ dst,
                   int K, int ldsrc)
{
    __shared__ float tle[32][33];
    const int n0 = blockIdx.x * 32, k0 = blockIdx.y * 32;
    const int tx = threadIdx.x & 31, ty = threadIdx.x >> 5;
#pragma unroll
    for (int j = 0; j < 4; j++)
        tle[ty + 8 * j][tx] = src[(long)(k0 + ty + 8 * j) * ldsrc + n0 + tx];
    __syncthreads();
#pragma unroll
    for (int j = 0; j < 4; j++)
        dst[(long)(n0 + ty + 8 * j) * K + k0 + tx] = f2bf(tle[tx][ty + 8 * j]);
}

// ---------------------------------------------------------------------------
// bf16 MFMA GEMM (as round 2, verified): C = alpha*A@Bt^T (+bias)
// ---------------------------------------------------------------------------
template<int GATHER, int OUTBF>
__global__ __launch_bounds__(256)
void gemm_bf16(const ushort_t* __restrict__ A, const ushort_t* __restrict__ Bt,
               void* __restrict__ Cv, int M, int Nn, int K,
               float alpha, const float* __restrict__ bias)
{
    __shared__ ushort_t As[128][32];
    __shared__ ushort_t Bs[128][32];

    const int tid = threadIdx.x;
    const int m0 = blockIdx.x * 128, n0 = blockIdx.y * 128;
    const int wave = tid >> 6, lane = tid & 63;
    const int wm = (wave & 1) * 64, wn = (wave >> 1) * 64;
    const int lrow = lane & 15, quad = lane >> 4;

    const int srow = tid >> 2, sseg = tid & 3;
    int ma0 = m0 + srow;      if (ma0 >= M) ma0 = M - 1;
    int ma1 = m0 + 64 + srow; if (ma1 >= M) ma1 = M - 1;
    long ra0, ra1;
    if (GATHER) {
        ra0 = (long)ma0 * F_ + (ma0 % S_) / P_;
        ra1 = (long)ma1 * F_ + (ma1 % S_) / P_;
    } else { ra0 = ma0; ra1 = ma1; }
    const ushort_t* ap0 = A + ra0 * K + sseg * 8;
    const ushort_t* ap1 = A + ra1 * K + sseg * 8;
    const ushort_t* bp0 = Bt + (long)(n0 + srow) * K + sseg * 8;
    const ushort_t* bp1 = Bt + (long)(n0 + 64 + srow) * K + sseg * 8;

    f32x4 acc[4][4];
#pragma unroll
    for (int i = 0; i < 4; i++)
#pragma unroll
        for (int j = 0; j < 4; j++) acc[i][j] = (f32x4){0.f, 0.f, 0.f, 0.f};

    uint4 aV0 = *(const uint4*)ap0;
    uint4 aV1 = *(const uint4*)ap1;
    uint4 bV0 = *(const uint4*)bp0;
    uint4 bV1 = *(const uint4*)bp1;

    const int nk = K >> 5;
    for (int kt = 0; kt < nk; kt++) {
        __syncthreads();
        *(uint4*)&As[srow][sseg * 8]      = aV0;
        *(uint4*)&As[64 + srow][sseg * 8] = aV1;
        *(uint4*)&Bs[srow][sseg * 8]      = bV0;
        *(uint4*)&Bs[64 + srow][sseg * 8] = bV1;
        __syncthreads();
        if (kt + 1 < nk) {
            int k0 = (kt + 1) * 32;
            aV0 = *(const uint4*)(ap0 + k0);
            aV1 = *(const uint4*)(ap1 + k0);
            bV0 = *(const uint4*)(bp0 + k0);
            bV1 = *(const uint4*)(bp1 + k0);
        }
        short8 af[4], bf[4];
#pragma unroll
        for (int mt = 0; mt < 4; mt++)
            af[mt] = *(const short8*)&As[wm + mt * 16 + lrow][quad * 8];
#pragma unroll
        for (int nt = 0; nt < 4; nt++)
            bf[nt] = *(const short8*)&Bs[wn + nt * 16 + lrow][quad * 8];
#pragma unroll
        for (int mt = 0; mt < 4; mt++)
#pragma unroll
            for (int nt = 0; nt < 4; nt++)
                acc[mt][nt] = __builtin_amdgcn_mfma_f32_16x16x32_bf16(
                    af[mt], bf[nt], acc[mt][nt], 0, 0, 0);
    }

#pragma unroll
    for (int mt = 0; mt < 4; mt++) {
#pragma unroll
        for (int nt = 0; nt < 4; nt++) {
            int row = m0 + wm + mt * 16 + quad * 4;
            int col = n0 + wn + nt * 16 + lrow;
            float bv = bias ? bias[col] : 0.f;
#pragma unroll
            for (int r = 0; r < 4; r++) {
                if (row + r < M) {
                    float v = acc[mt][nt][r] * alpha + bv;
                    if (OUTBF)
                        ((ushort_t*)Cv)[(long)(row + r) * Nn + col] = f2bf(v);
                    else
                        ((float*)Cv)[(long)(row + r) * Nn + col] = v;
                }
            }
        }
    }
}

// ---------------------------------------------------------------------------
// Pre-pass: qkv fp32 -> MFMA-friendly bf16 layouts.
// q_bf  [b][h][1568][64]
// k_bf  [b][h][f]: 2 k-planes x [208 keys][32]   (keys 196..207 zeroed)
// vT_bf [b][h][f]: [64 d][224 keys]              (keys 196..223 zeroed)
// grid (8 f, 12 h, 2 b), 256 threads
// ---------------------------------------------------------------------------
__global__ __launch_bounds__(256)
void prep_kv(const float* __restrict__ qkv, ushort_t* __restrict__ q_bf,
             ushort_t* __restrict__ k_bf, ushort_t* __restrict__ vT_bf)
{
    const int f = blockIdx.x, h = blockIdx.y, b = blockIdx.z;
    const int t = threadIdx.x;
    const long rowbase = (long)(b * N_ + 1 + f * P_) * QKVLD;

    // q: 196 rows x 16 float4 segs
    {
        ushort_t* qd = q_bf + ((long)(b * H_ + h) * S_ + f * P_) * 64;
        for (int u = t; u < P_ * 16; u += 256) {
            int row = u >> 4, seg = u & 15;
            float4 v = *(const float4*)(qkv + rowbase + (long)row * QKVLD + h * 64 + seg * 4);
            *(uint2*)(qd + (long)row * 64 + seg * 4) = pack4(v.x, v.y, v.z, v.w);
        }
    }
    // k: 208 keys x 16 segs (zero-pad keys >= 196)
    {
        ushort_t* kd = k_bf + (long)((b * H_ + h) * F_ + f) * 13312;
        for (int u = t; u < 208 * 16; u += 256) {
            int key = u >> 4, seg = u & 15, d = seg * 4;
            float4 v = make_float4(0.f, 0.f, 0.f, 0.f);
            if (key < P_)
                v = *(const float4*)(qkv + rowbase + (long)key * QKVLD + 768 + h * 64 + d);
            *(uint2*)(kd + (d >> 5) * 6656 + key * 32 + (d & 31)) = pack4(v.x, v.y, v.z, v.w);
        }
    }
    // v transpose via LDS
    __shared__ float Vl[224][68];
    for (int u = t; u < 224 * 16; u += 256) {
        int key = u >> 4, seg = u & 15;
        float4 v = make_float4(0.f, 0.f, 0.f, 0.f);
        if (key < P_)
            v = *(const float4*)(qkv + rowbase + (long)key * QKVLD + 1536 + h * 64 + seg * 4);
        *(float4*)&Vl[key][seg * 4] = v;
    }
    __syncthreads();
    {
        ushort_t* vd = vT_bf + (long)((b * H_ + h) * F_ + f) * 14336;
        for (int u = t; u < 64 * 56; u += 256) {
            int d = u / 56, kb = u % 56;
            *(uint2*)(vd + d * 224 + kb * 4) =
                pack4(Vl[kb*4+0][d], Vl[kb*4+1][d], Vl[kb*4+2][d], Vl[kb*4+3][d]);
        }
    }
}

// ---------------------------------------------------------------------------
// MFMA trajectory attention. Block = (qt, h, b), 256 thr = 4 waves.
// 64 queries/block, f-loop inside. Wave w owns query m-tile w (16 rows).
// Per frame: QK^T (13 n-tiles x 2 k) -> register softmax (C-layout:
// row=quad*4+reg, col=lane&15; shfl_xor width-16 across key phases) ->
// unnormalized P (bf16) to LDS -> PV (7 k-steps x 4 n-tiles), 1/l in epilogue.
// LDS 65 KB -> 2 blocks/CU.
// ---------------------------------------------------------------------------
__global__ __launch_bounds__(256, 2)
void traj_attn_mfma(const ushort_t* __restrict__ q_bf,
                    const ushort_t* __restrict__ k_bf,
                    const ushort_t* __restrict__ vT_bf,
                    ushort_t* __restrict__ traj)
{
    __shared__ __align__(16) ushort_t Qs[2 * 64 * 32];    // 8192 B
    __shared__ __align__(16) ushort_t KV[14336];          // 28672 B (K:26624 / Vt:28672)
    __shared__ __align__(16) ushort_t Pl[64 * 232];       // 29696 B

    const int t = threadIdx.x;
    const int wave = t >> 6, lane = t & 63;
    const int lrow = lane & 15, quad = lane >> 4;
    const int qt = blockIdx.x, h = blockIdx.y, b = blockIdx.z;
    const int s0 = qt * 64;
    const bool v12 = (lrow < 4);       // tile-12 key validity (keys 192..195)

    // stage Q: 64 rows x 64 d -> 2 k-planes x [64][32]
    {
        const ushort_t* qb = q_bf + (long)(b * H_ + h) * S_ * 64;
#pragma unroll
        for (int u = t; u < 512; u += 256) {
            int i = u >> 3, seg = u & 7;
            int srow = s0 + i; if (srow > S_ - 1) srow = S_ - 1;
            uint4 v = *(const uint4*)(qb + (long)srow * 64 + seg * 8);
            *(uint4*)&Qs[(seg >> 2) * 2048 + i * 32 + (seg & 3) * 8] = v;
        }
    }
    // zero P cols 208..223 (read by PV k-step 6, never written per-frame)
    if (t < 128) {
        int row = t >> 1, c = t & 1;
        *(uint4*)&Pl[row * 232 + 208 + c * 8] = (uint4){0, 0, 0, 0};
    }
    __syncthreads();

    // Q fragments live across all frames
    short8 a0 = *(const short8*)&Qs[0 * 2048 + (wave * 16 + lrow) * 32 + quad * 8];
    short8 a1 = *(const short8*)&Qs[1 * 2048 + (wave * 16 + lrow) * 32 + quad * 8];

    const ushort_t* kfb = k_bf  + (long)((b * H_ + h) * F_) * 13312;
    const ushort_t* vfb = vT_bf + (long)((b * H_ + h) * F_) * 14336;

    for (int f = 0; f < F_; f++) {
        __syncthreads();                       // prev PV done with KV & Pl
        // stage K (linear copy, 26624 B)
        {
            const ushort_t* kf = kfb + (long)f * 13312;
            for (int u = t; u < 1664; u += 256)
                *(uint4*)&KV[u * 8] = *(const uint4*)(kf + u * 8);
        }
        __syncthreads();

        // QK^T: 13 n-tiles x 2 k-steps
        f32x4 acc[13];
#pragma unroll
        for (int nt = 0; nt < 13; nt++) acc[nt] = (f32x4){0.f, 0.f, 0.f, 0.f};
#pragma unroll
        for (int nt = 0; nt < 13; nt++) {
            short8 bv = *(const short8*)&KV[(nt * 16 + lrow) * 32 + quad * 8];
            acc[nt] = __builtin_amdgcn_mfma_f32_16x16x32_bf16(a0, bv, acc[nt], 0, 0, 0);
        }
#pragma unroll
        for (int nt = 0; nt < 13; nt++) {
            short8 bv = *(const short8*)&KV[6656 + (nt * 16 + lrow) * 32 + quad * 8];
            acc[nt] = __builtin_amdgcn_mfma_f32_16x16x32_bf16(a1, bv, acc[nt], 0, 0, 0);
        }
        __syncthreads();                       // QK reads done; KV reusable

        // stage Vt over K (28672 B) — loads overlap register softmax
        {
            const ushort_t* vf = vfb + (long)f * 14336;
            for (int u = t; u < 1792; u += 256)
                *(uint4*)&KV[u * 8] = *(const uint4*)(vf + u * 8);
        }

        // register softmax over keys (max-subtracted, unnormalized P)
        float rl[4];
#pragma unroll
        for (int r = 0; r < 4; r++) {
            float mx = acc[0][r];
#pragma unroll
            for (int nt = 1; nt < 12; nt++) mx = fmaxf(mx, acc[nt][r]);
            if (v12) mx = fmaxf(mx, acc[12][r]);
#pragma unroll
            for (int off = 1; off < 16; off <<= 1)
                mx = fmaxf(mx, __shfl_xor(mx, off, 16));
            float sum = 0.f;
#pragma unroll
            for (int nt = 0; nt < 12; nt++) {
                float w = __expf((acc[nt][r] - mx) * SCALE);
                acc[nt][r] = w; sum += w;
            }
            {
                float w = v12 ? __expf((acc[12][r] - mx) * SCALE) : 0.f;
                acc[12][r] = w; sum += w;
            }
#pragma unroll
            for (int off = 1; off < 16; off <<= 1)
                sum += __shfl_xor(sum, off, 16);
            rl[r] = 1.f / sum;
        }

        // write P (bf16) rows wave*16+quad*4+r, col nt*16+lrow
#pragma unroll
        for (int nt = 0; nt < 13; nt++)
#pragma unroll
            for (int r = 0; r < 4; r++)
                Pl[(wave * 16 + quad * 4 + r) * 232 + nt * 16 + lrow] = f2bf(acc[nt][r]);

        __syncthreads();                       // Vt staged + P written

        // PV: rows = wave m-tile, 4 d-tiles, k = 224 (7 steps)
        f32x4 av[4];
#pragma unroll
        for (int nt = 0; nt < 4; nt++) av[nt] = (f32x4){0.f, 0.f, 0.f, 0.f};
#pragma unroll
        for (int s = 0; s < 7; s++) {
            short8 af = *(const short8*)&Pl[(wave * 16 + lrow) * 232 + s * 32 + quad * 8];
#pragma unroll
            for (int nt = 0; nt < 4; nt++) {
                short8 bv = *(const short8*)&KV[(nt * 16 + lrow) * 224 + s * 32 + quad * 8];
                av[nt] = __builtin_amdgcn_mfma_f32_16x16x32_bf16(af, bv, av[nt], 0, 0, 0);
            }
        }

        // epilogue: scale by 1/l, write traj[b][s][f][h*64+d]
#pragma unroll
        for (int nt = 0; nt < 4; nt++)
#pragma unroll
            for (int r = 0; r < 4; r++) {
                int so = s0 + wave * 16 + quad * 4 + r;
                if (so < S_)
                    traj[((long)(b * S_ + so) * F_ + f) * C_ + h * 64 + nt * 16 + lrow]
                        = f2bf(av[nt][r] * rl[r]);
            }
    }
}

// ---------------------------------------------------------------------------
// CLS attention (fp32, unchanged)
// ---------------------------------------------------------------------------
__global__ __launch_bounds__(256)
void cls_attn(const float* __restrict__ qkv, float* __restrict__ outcat)
{
    const int bh = blockIdx.x;
    const int b = bh / H_, hh = bh % H_;
    __shared__ float qs[64];
    __shared__ float sc[N_];
    __shared__ float red[256];
    const int t = threadIdx.x;

    const float* qrow = qkv + (long)(b * N_) * QKVLD + hh * 64;
    if (t < 64) qs[t] = qrow[t];
    __syncthreads();

    float lmax = -1e30f;
    for (int n = t; n < N_; n += 256) {
        const float* krow = qkv + (long)(b * N_ + n) * QKVLD + 768 + hh * 64;
        float acc = 0.f;
#pragma unroll
        for (int j4 = 0; j4 < 16; j4++) {
            float4 kv = *(const float4*)(krow + j4 * 4);
            acc = fmaf(kv.x, qs[j4*4+0], acc);
            acc = fmaf(kv.y, qs[j4*4+1], acc);
            acc = fmaf(kv.z, qs[j4*4+2], acc);
            acc = fmaf(kv.w, qs[j4*4+3], acc);
        }
        acc *= SCALE;
        sc[n] = acc;
        lmax = fmaxf(lmax, acc);
    }
    red[t] = lmax;
    __syncthreads();
    for (int s = 128; s > 0; s >>= 1) {
        if (t < s) red[t] = fmaxf(red[t], red[t + s]);
        __syncthreads();
    }
    float m = red[0];
    __syncthreads();

    float lsum = 0.f;
    for (int n = t; n < N_; n += 256) {
        float w = __expf(sc[n] - m);
        sc[n] = w;
        lsum += w;
    }
    red[t] = lsum;
    __syncthreads();
    for (int s = 128; s > 0; s >>= 1) {
        if (t < s) red[t] += red[t + s];
        __syncthreads();
    }
    float rsum = 1.f / red[0];

    const int j = t & 63, part = t >> 6;
    float acc = 0.f;
    for (int n = part; n < N_; n += 4)
        acc = fmaf(sc[n], qkv[(long)(b * N_ + n) * QKVLD + 1536 + hh * 64 + j], acc);
    __syncthreads();
    red[t] = acc;
    __syncthreads();
    if (t < 64) {
        float o = (red[t] + red[64 + t] + red[128 + t] + red[192 + t]) * rsum;
        outcat[(long)(b * N_) * C_ + hh * 64 + t] = o;
    }
}

// ---------------------------------------------------------------------------
// Second attention over F=8 + weighted traj sum (unchanged)
// ---------------------------------------------------------------------------
__global__ __launch_bounds__(256)
void attn2_kernel(const float* __restrict__ q2, const ushort_t* __restrict__ k2,
                  const ushort_t* __restrict__ traj, float* __restrict__ outcat,
                  float* __restrict__ attn_out)
{
    const int bs = blockIdx.x;
    const int b = bs / S_, s = bs % S_;
    __shared__ float qs[768];
    __shared__ float ks[8][768];
    __shared__ float logit[12][8];
    __shared__ float wsm[12][8];
    const int t = threadIdx.x;

    const float* qrow = q2 + (long)bs * 768;
    for (int c = t; c < 768; c += 256) qs[c] = qrow[c];
    const ushort_t* krow = k2 + (long)bs * 8 * 768;
    for (int idx = t; idx < 8 * 768; idx += 256)
        ks[idx / 768][idx % 768] = bf2f(krow[idx]);
    __syncthreads();

    if (t < 96) {
        int hh = t >> 3, f = t & 7;
        float acc = 0.f;
#pragma unroll 8
        for (int j = 0; j < 64; j++)
            acc = fmaf(qs[hh * 64 + j], ks[f][hh * 64 + j], acc);
        logit[hh][f] = acc;
    }
    __syncthreads();
    if (t < 12) {
        float m = logit[t][0];
#pragma unroll
        for (int f = 1; f < 8; f++) m = fmaxf(m, logit[t][f]);
        float w[8], sum = 0.f;
#pragma unroll
        for (int f = 0; f < 8; f++) { w[f] = __expf(logit[t][f] - m); sum += w[f]; }
        float r = 1.f / sum;
#pragma unroll
        for (int f = 0; f < 8; f++) wsm[t][f] = w[f] * r;
    }
    __syncthreads();
    if (t < 96) {
        int hh = t >> 3, f = t & 7;
        attn_out[((long)(b * H_ + hh) * S_ + s) * 8 + f] = wsm[hh][f];
    }
    const ushort_t* trow = traj + (long)bs * 8 * 768;
    float* orow = outcat + ((long)(b * N_) + 1 + s) * 768;
    for (int c = t; c < 768; c += 256) {
        int hh = c >> 6;
        float acc = 0.f;
#pragma unroll
        for (int f = 0; f < 8; f++)
            acc = fmaf(wsm[hh][f], bf2f(trow[f * 768 + c]), acc);
        orow[c] = acc;
    }
}

// ---------------------------------------------------------------------------
extern "C" void kernel_launch(void* const* d_in, const int* in_sizes, int n_in,
                              void* d_out, int out_size, void* d_ws, size_t ws_size,
                              hipStream_t stream)
{
    (void)in_sizes; (void)n_in; (void)out_size; (void)ws_size;
    const float* x     = (const float*)d_in[0];
    const float* Wqkv  = (const float*)d_in[1];
    const float* Wpq   = (const float*)d_in[2];
    const float* Wpkv  = (const float*)d_in[3];
    const float* Wproj = (const float*)d_in[4];
    const float* bproj = (const float*)d_in[5];
    float* out = (float*)d_out;

    char* p = (char*)d_ws;
    // region A: qkv f32 (28.9 MB), later overwritten by traj_bf (38.5 MB)
    float*    qkv     = (float*)p;
    ushort_t* traj_bf = (ushort_t*)p;
    p += (size_t)25088 * 768 * 2;
    float* q2 = (float*)p;  p += (size_t)3136 * 768 * 4;
    // region C: [x_bf | q_bf | k_bf | vT_bf] early, k2_bf (38.5 MB) late
    char* c0 = p;
    ushort_t* k2_bf = (ushort_t*)c0;
    ushort_t* x_bf  = (ushort_t*)c0;
    ushort_t* q_bf  = (ushort_t*)(c0 + (size_t)4819968);
    ushort_t* k_bf  = (ushort_t*)(c0 + (size_t)4819968 + 4816896);
    ushort_t* vT_bf = (ushort_t*)(c0 + (size_t)4819968 + 4816896 + 5111808);
    p += (size_t)25088 * 768 * 2;
    float*    outcat    = (float*)p;     p += (size_t)3138 * 768 * 4;
    ushort_t* outcat_bf = (ushort_t*)p;  p += (size_t)3138 * 768 * 2;
    ushort_t* Wqkv_t  = (ushort_t*)p;    p += (size_t)1769472 * 2;
    ushort_t* Wpq_t   = (ushort_t*)p;    p += (size_t)589824 * 2;
    ushort_t* Wpkv_t  = (ushort_t*)p;    p += (size_t)589824 * 2;
    ushort_t* Wproj_t = (ushort_t*)p;    p += (size_t)589824 * 2;
    float* attn_out = out + (size_t)3138 * 768;

    // input conversions
    cvt_f32_bf16<<<2354, 256, 0, stream>>>(x, x_bf, 602496);
    transpose_cvt<<<dim3(72, 24), 256, 0, stream>>>(Wqkv,  Wqkv_t,  768, 2304);
    transpose_cvt<<<dim3(24, 24), 256, 0, stream>>>(Wpq,   Wpq_t,   768, 768);
    transpose_cvt<<<dim3(24, 24), 256, 0, stream>>>(Wpkv,  Wpkv_t,  768, 1536);
    transpose_cvt<<<dim3(24, 24), 256, 0, stream>>>(Wproj, Wproj_t, 768, 768);

    // 1. qkv = x @ W_qkv  (fp32 out)
    gemm_bf16<0, 0><<<dim3(25, 18), 256, 0, stream>>>(x_bf, Wqkv_t, qkv, 3138, 2304, 768, 1.f, nullptr);
    // 2. reshape to MFMA-friendly bf16 layouts
    prep_kv<<<dim3(8, 12, 2), 256, 0, stream>>>(qkv, q_bf, k_bf, vT_bf);
    // 3. CLS attention -> outcat row 0 (last reader of fp32 qkv)
    cls_attn<<<24, 256, 0, stream>>>(qkv, outcat);
    // 4. MFMA trajectory attention -> traj_bf (overwrites qkv region)
    traj_attn_mfma<<<dim3(25, 12, 2), 256, 0, stream>>>(q_bf, k_bf, vT_bf, traj_bf);
    // 5. q2 = (x_diag @ W_pq) * scale
    gemm_bf16<1, 0><<<dim3(25, 6), 256, 0, stream>>>(traj_bf, Wpq_t, q2, 3136, 768, 768, SCALE, nullptr);
    // 6. k2 = traj @ W_pkv[:, :768] -> bf16 (overwrites x/q/k/vT buffers)
    gemm_bf16<0, 1><<<dim3(196, 6), 256, 0, stream>>>(traj_bf, Wpkv_t, k2_bf, 25088, 768, 768, 1.f, nullptr);
    // 7. F-attention + weighted traj sum
    attn2_kernel<<<3136, 256, 0, stream>>>(q2, k2_bf, traj_bf, outcat, attn_out);
    // 8. out = outcat @ W_proj + b_proj
    cvt_f32_bf16<<<2354, 256, 0, stream>>>(outcat, outcat_bf, 602496);
    gemm_bf16<0, 0><<<dim3(25, 6), 256, 0, stream>>>(outcat_bf, Wproj_t, out, 3138, 768, 768, 1.f, bproj);
}

// Round 4
// 437.365 us; speedup vs baseline: 3.2322x; 1.1460x over previous
//
#include <hip/hip_runtime.h>

#define B_ 2
#define N_ 1569
#define C_ 768
#define H_ 12
#define D_ 64
#define P_ 196
#define F_ 8
#define S_ 1568
#define QKVLD 2304
#define SCALE 0.125f

typedef unsigned short ushort_t;
using short8 = __attribute__((ext_vector_type(8))) short;
using f32x4  = __attribute__((ext_vector_type(4))) float;

__device__ __forceinline__ ushort_t f2bf(float x) {
    unsigned u = __float_as_uint(x);
    u += 0x7fffu + ((u >> 16) & 1);       // RNE
    return (ushort_t)(u >> 16);
}
__device__ __forceinline__ float bf2f(ushort_t h) {
    return __uint_as_float((unsigned)h << 16);
}
__device__ __forceinline__ uint2 pack4(float a, float b, float c, float d) {
    uint2 o;
    o.x = f2bf(a) | ((unsigned)f2bf(b) << 16);
    o.y = f2bf(c) | ((unsigned)f2bf(d) << 16);
    return o;
}

// ---------------------------------------------------------------------------
// fp32 -> bf16 elementwise convert (n4 = n/4 float4 groups)
// ---------------------------------------------------------------------------
__global__ __launch_bounds__(256)
void cvt_f32_bf16(const float* __restrict__ s, ushort_t* __restrict__ d, int n4)
{
    int i = blockIdx.x * 256 + threadIdx.x;
    if (i < n4) {
        float4 v = ((const float4*)s)[i];
        ((uint2*)d)[i] = pack4(v.x, v.y, v.z, v.w);
    }
}

// ---------------------------------------------------------------------------
// Transpose+convert weights: src (K x ldsrc fp32) -> dst (N x K bf16)
// ---------------------------------------------------------------------------
__global__ __launch_bounds__(256)
void transpose_cvt(const float* __restrict__ src, ushort_t* __restrict__ dst,
                   int K, int ldsrc)
{
    __shared__ float tle[32][33];
    const int n0 = blockIdx.x * 32, k0 = blockIdx.y * 32;
    const int tx = threadIdx.x & 31, ty = threadIdx.x >> 5;
#pragma unroll
    for (int j = 0; j < 4; j++)
        tle[ty + 8 * j][tx] = src[(long)(k0 + ty + 8 * j) * ldsrc + n0 + tx];
    __syncthreads();
#pragma unroll
    for (int j = 0; j < 4; j++)
        dst[(long)(n0 + ty + 8 * j) * K + k0 + tx] = f2bf(tle[tx][ty + 8 * j]);
}

// ---------------------------------------------------------------------------
// bf16 MFMA GEMM (verified r2/r3): C = alpha*A@Bt^T (+bias)
// ---------------------------------------------------------------------------
template<int GATHER, int OUTBF>
__global__ __launch_bounds__(256)
void gemm_bf16(const ushort_t* __restrict__ A, const ushort_t* __restrict__ Bt,
               void* __restrict__ Cv, int M, int Nn, int K,
               float alpha, const float* __restrict__ bias)
{
    __shared__ ushort_t As[128][32];
    __shared__ ushort_t Bs[128][32];

    const int tid = threadIdx.x;
    const int m0 = blockIdx.x * 128, n0 = blockIdx.y * 128;
    const int wave = tid >> 6, lane = tid & 63;
    const int wm = (wave & 1) * 64, wn = (wave >> 1) * 64;
    const int lrow = lane & 15, quad = lane >> 4;

    const int srow = tid >> 2, sseg = tid & 3;
    int ma0 = m0 + srow;      if (ma0 >= M) ma0 = M - 1;
    int ma1 = m0 + 64 + srow; if (ma1 >= M) ma1 = M - 1;
    long ra0, ra1;
    if (GATHER) {
        ra0 = (long)ma0 * F_ + (ma0 % S_) / P_;
        ra1 = (long)ma1 * F_ + (ma1 % S_) / P_;
    } else { ra0 = ma0; ra1 = ma1; }
    const ushort_t* ap0 = A + ra0 * K + sseg * 8;
    const ushort_t* ap1 = A + ra1 * K + sseg * 8;
    const ushort_t* bp0 = Bt + (long)(n0 + srow) * K + sseg * 8;
    const ushort_t* bp1 = Bt + (long)(n0 + 64 + srow) * K + sseg * 8;

    f32x4 acc[4][4];
#pragma unroll
    for (int i = 0; i < 4; i++)
#pragma unroll
        for (int j = 0; j < 4; j++) acc[i][j] = (f32x4){0.f, 0.f, 0.f, 0.f};

    uint4 aV0 = *(const uint4*)ap0;
    uint4 aV1 = *(const uint4*)ap1;
    uint4 bV0 = *(const uint4*)bp0;
    uint4 bV1 = *(const uint4*)bp1;

    const int nk = K >> 5;
    for (int kt = 0; kt < nk; kt++) {
        __syncthreads();
        *(uint4*)&As[srow][sseg * 8]      = aV0;
        *(uint4*)&As[64 + srow][sseg * 8] = aV1;
        *(uint4*)&Bs[srow][sseg * 8]      = bV0;
        *(uint4*)&Bs[64 + srow][sseg * 8] = bV1;
        __syncthreads();
        if (kt + 1 < nk) {
            int k0 = (kt + 1) * 32;
            aV0 = *(const uint4*)(ap0 + k0);
            aV1 = *(const uint4*)(ap1 + k0);
            bV0 = *(const uint4*)(bp0 + k0);
            bV1 = *(const uint4*)(bp1 + k0);
        }
        short8 af[4], bf[4];
#pragma unroll
        for (int mt = 0; mt < 4; mt++)
            af[mt] = *(const short8*)&As[wm + mt * 16 + lrow][quad * 8];
#pragma unroll
        for (int nt = 0; nt < 4; nt++)
            bf[nt] = *(const short8*)&Bs[wn + nt * 16 + lrow][quad * 8];
#pragma unroll
        for (int mt = 0; mt < 4; mt++)
#pragma unroll
            for (int nt = 0; nt < 4; nt++)
                acc[mt][nt] = __builtin_amdgcn_mfma_f32_16x16x32_bf16(
                    af[mt], bf[nt], acc[mt][nt], 0, 0, 0);
    }

#pragma unroll
    for (int mt = 0; mt < 4; mt++) {
#pragma unroll
        for (int nt = 0; nt < 4; nt++) {
            int row = m0 + wm + mt * 16 + quad * 4;
            int col = n0 + wn + nt * 16 + lrow;
            float bv = bias ? bias[col] : 0.f;
#pragma unroll
            for (int r = 0; r < 4; r++) {
                if (row + r < M) {
                    float v = acc[mt][nt][r] * alpha + bv;
                    if (OUTBF)
                        ((ushort_t*)Cv)[(long)(row + r) * Nn + col] = f2bf(v);
                    else
                        ((float*)Cv)[(long)(row + r) * Nn + col] = v;
                }
            }
        }
    }
}

// ---------------------------------------------------------------------------
// Pre-pass: qkv fp32 -> fragment-major bf16 layouts for barrier-free attn.
// q_bf   [b][h][1568][64]  (row-major)
// k_frag [b][h][f][ks(2)][nt(13)][lane(64)][8] : = K[key=nt*16+(lane&15)]
//                                                  [d = ks*32+(lane>>4)*8+j]
// vT_frag[b][h][f][s(7)][nt(4)][lane(64)][8]   : = V[key=s*32+(lane>>4)*8+j]
//                                                  [d = nt*16+(lane&15)]
// keys >= 196 zero-padded. grid (8 f, 12 h, 2 b), 256 threads.
// ---------------------------------------------------------------------------
__global__ __launch_bounds__(256)
void prep_kv(const float* __restrict__ qkv, ushort_t* __restrict__ q_bf,
             ushort_t* __restrict__ k_bf, ushort_t* __restrict__ vT_bf)
{
    const int f = blockIdx.x, h = blockIdx.y, b = blockIdx.z;
    const int t = threadIdx.x;
    const long rowbase = (long)(b * N_ + 1 + f * P_) * QKVLD;

    // q: 196 rows x 16 float4 segs
    {
        ushort_t* qd = q_bf + ((long)(b * H_ + h) * S_ + f * P_) * 64;
        for (int u = t; u < P_ * 16; u += 256) {
            int row = u >> 4, seg = u & 15;
            float4 v = *(const float4*)(qkv + rowbase + (long)row * QKVLD + h * 64 + seg * 4);
            *(uint2*)(qd + (long)row * 64 + seg * 4) = pack4(v.x, v.y, v.z, v.w);
        }
    }
    // k fragment-major: 208 keys x 16 segs (d0 = seg*4)
    {
        ushort_t* kd = k_bf + (long)((b * H_ + h) * F_ + f) * 13312;
        for (int u = t; u < 208 * 16; u += 256) {
            int key = u >> 4, seg = u & 15;
            float4 v = make_float4(0.f, 0.f, 0.f, 0.f);
            if (key < P_)
                v = *(const float4*)(qkv + rowbase + (long)key * QKVLD + 768 + h * 64 + seg * 4);
            int ks = seg >> 3, qq = (seg >> 1) & 3, j0 = (seg & 1) * 4;
            int nt = key >> 4, lr = key & 15;
            *(uint2*)(kd + ((ks * 13 + nt) * 64 + qq * 16 + lr) * 8 + j0)
                = pack4(v.x, v.y, v.z, v.w);
        }
    }
    // v transpose via LDS, then fragment-major
    __shared__ float Vl[224][68];
    for (int u = t; u < 224 * 16; u += 256) {
        int key = u >> 4, seg = u & 15;
        float4 v = make_float4(0.f, 0.f, 0.f, 0.f);
        if (key < P_)
            v = *(const float4*)(qkv + rowbase + (long)key * QKVLD + 1536 + h * 64 + seg * 4);
        *(float4*)&Vl[key][seg * 4] = v;
    }
    __syncthreads();
    {
        ushort_t* vd = vT_bf + (long)((b * H_ + h) * F_ + f) * 14336;
        for (int u = t; u < 64 * 56; u += 256) {
            int d = u / 56, kb = u % 56;      // keys kb*4..+3
            int s = kb >> 3, qq = (kb >> 1) & 3, j0 = (kb & 1) * 4;
            int nt = d >> 4, lr = d & 15;
            *(uint2*)(vd + ((s * 4 + nt) * 64 + qq * 16 + lr) * 8 + j0) =
                pack4(Vl[kb*4+0][d], Vl[kb*4+1][d], Vl[kb*4+2][d], Vl[kb*4+3][d]);
        }
    }
}

// ---------------------------------------------------------------------------
// Barrier-free MFMA trajectory attention. Block = (qt, h, b), 256 thr = 4
// waves; wave w owns 16 query rows. B-fragments (K, Vt) loaded directly from
// global (fragment-major, 1 KB coalesced dwordx4 per fragment). P transpose
// goes through wave-PRIVATE LDS (s_waitcnt lgkmcnt only, no __syncthreads).
// LDS 28.7 KB. Zero block barriers in the f-loop.
// ---------------------------------------------------------------------------
__global__ __launch_bounds__(256)
void traj_attn_mfma(const ushort_t* __restrict__ q_bf,
                    const ushort_t* __restrict__ k_bf,
                    const ushort_t* __restrict__ vT_bf,
                    ushort_t* __restrict__ traj)
{
    // per-wave private P fragments: [s(7)][lane(64)][8]
    __shared__ __align__(16) ushort_t Pl[4][7 * 512];

    const int t = threadIdx.x;
    const int wave = t >> 6, lane = t & 63;
    const int lrow = lane & 15, quad = lane >> 4;
    const int qt = blockIdx.x, h = blockIdx.y, b = blockIdx.z;
    const int s0 = qt * 64;
    const bool v12 = (lrow < 4);   // n-tile 12: keys 192..195 valid

    // Q fragments straight from global (row-clamped)
    int qrow = s0 + wave * 16 + lrow; if (qrow > S_ - 1) qrow = S_ - 1;
    const ushort_t* qp = q_bf + ((long)(b * H_ + h) * S_ + qrow) * 64 + quad * 8;
    short8 a0 = *(const short8*)qp;
    short8 a1 = *(const short8*)(qp + 32);

    // zero P keys 208..223 once (never written in the f-loop)
    *(uint2*)&Pl[wave][6 * 512 + 256 + lane * 4] = (uint2){0, 0};

    const ushort_t* kfb = k_bf  + (long)((b * H_ + h) * F_) * 13312;
    const ushort_t* vfb = vT_bf + (long)((b * H_ + h) * F_) * 14336;

#pragma unroll 1
    for (int f = 0; f < F_; f++) {
        const ushort_t* kf = kfb + (long)f * 13312;
        const ushort_t* vf = vfb + (long)f * 14336;

        // QK^T: 13 n-tiles x 2 k-steps, B-fragments direct from global
        f32x4 acc[13];
#pragma unroll
        for (int nt = 0; nt < 13; nt++) acc[nt] = (f32x4){0.f, 0.f, 0.f, 0.f};
#pragma unroll
        for (int nt = 0; nt < 13; nt++) {
            short8 bv = *(const short8*)(kf + (long)nt * 512 + lane * 8);
            acc[nt] = __builtin_amdgcn_mfma_f32_16x16x32_bf16(a0, bv, acc[nt], 0, 0, 0);
        }
#pragma unroll
        for (int nt = 0; nt < 13; nt++) {
            short8 bv = *(const short8*)(kf + (long)(13 + nt) * 512 + lane * 8);
            acc[nt] = __builtin_amdgcn_mfma_f32_16x16x32_bf16(a1, bv, acc[nt], 0, 0, 0);
        }

        // register softmax over keys (C layout: row=quad*4+r, col=nt*16+lrow)
        float rl[4];
#pragma unroll
        for (int r = 0; r < 4; r++) {
            float mx = acc[0][r];
#pragma unroll
            for (int nt = 1; nt < 12; nt++) mx = fmaxf(mx, acc[nt][r]);
            if (v12) mx = fmaxf(mx, acc[12][r]);
#pragma unroll
            for (int off = 1; off < 16; off <<= 1)
                mx = fmaxf(mx, __shfl_xor(mx, off, 16));
            float sum = 0.f;
#pragma unroll
            for (int nt = 0; nt < 12; nt++) {
                float w = __expf((acc[nt][r] - mx) * SCALE);
                acc[nt][r] = w; sum += w;
            }
            {
                float w = v12 ? __expf((acc[12][r] - mx) * SCALE) : 0.f;
                acc[12][r] = w; sum += w;
            }
#pragma unroll
            for (int off = 1; off < 16; off <<= 1)
                sum += __shfl_xor(sum, off, 16);
            rl[r] = 1.f / sum;
        }

        // P -> wave-private LDS in A-fragment order:
        // element (m=quad*4+r, key=nt*16+lrow) -> [(key>>5)*512 + ((key>>3)&3)*128 + m*8 + (key&7)]
#pragma unroll
        for (int nt = 0; nt < 13; nt++) {
            int key = nt * 16 + lrow;
            int base = (key >> 5) * 512 + ((key >> 3) & 3) * 128 + (key & 7) + quad * 32;
#pragma unroll
            for (int r = 0; r < 4; r++)
                Pl[wave][base + r * 8] = f2bf(acc[nt][r]);
        }
        // in-wave LDS write->read ordering (wave-private rows; no block barrier)
        asm volatile("s_waitcnt lgkmcnt(0)" ::: "memory");

        // PV: A = P fragments (b128 from private LDS), B = Vt direct global
        f32x4 av[4];
#pragma unroll
        for (int nt = 0; nt < 4; nt++) av[nt] = (f32x4){0.f, 0.f, 0.f, 0.f};
#pragma unroll
        for (int s = 0; s < 7; s++) {
            short8 af = *(const short8*)&Pl[wave][s * 512 + lane * 8];
#pragma unroll
            for (int nt = 0; nt < 4; nt++) {
                short8 bv = *(const short8*)(vf + (long)(s * 4 + nt) * 512 + lane * 8);
                av[nt] = __builtin_amdgcn_mfma_f32_16x16x32_bf16(af, bv, av[nt], 0, 0, 0);
            }
        }

        // epilogue: 1/l scale, store traj[b][s][f][h*64+d]
#pragma unroll
        for (int nt = 0; nt < 4; nt++)
#pragma unroll
            for (int r = 0; r < 4; r++) {
                int so = s0 + wave * 16 + quad * 4 + r;
                if (so < S_)
                    traj[((long)(b * S_ + so) * F_ + f) * C_ + h * 64 + nt * 16 + lrow]
                        = f2bf(av[nt][r] * rl[r]);
            }
    }
}

// ---------------------------------------------------------------------------
// CLS attention (fp32, unchanged)
// ---------------------------------------------------------------------------
__global__ __launch_bounds__(256)
void cls_attn(const float* __restrict__ qkv, float* __restrict__ outcat)
{
    const int bh = blockIdx.x;
    const int b = bh / H_, hh = bh % H_;
    __shared__ float qs[64];
    __shared__ float sc[N_];
    __shared__ float red[256];
    const int t = threadIdx.x;

    const float* qrow = qkv + (long)(b * N_) * QKVLD + hh * 64;
    if (t < 64) qs[t] = qrow[t];
    __syncthreads();

    float lmax = -1e30f;
    for (int n = t; n < N_; n += 256) {
        const float* krow = qkv + (long)(b * N_ + n) * QKVLD + 768 + hh * 64;
        float acc = 0.f;
#pragma unroll
        for (int j4 = 0; j4 < 16; j4++) {
            float4 kv = *(const float4*)(krow + j4 * 4);
            acc = fmaf(kv.x, qs[j4*4+0], acc);
            acc = fmaf(kv.y, qs[j4*4+1], acc);
            acc = fmaf(kv.z, qs[j4*4+2], acc);
            acc = fmaf(kv.w, qs[j4*4+3], acc);
        }
        acc *= SCALE;
        sc[n] = acc;
        lmax = fmaxf(lmax, acc);
    }
    red[t] = lmax;
    __syncthreads();
    for (int s = 128; s > 0; s >>= 1) {
        if (t < s) red[t] = fmaxf(red[t], red[t + s]);
        __syncthreads();
    }
    float m = red[0];
    __syncthreads();

    float lsum = 0.f;
    for (int n = t; n < N_; n += 256) {
        float w = __expf(sc[n] - m);
        sc[n] = w;
        lsum += w;
    }
    red[t] = lsum;
    __syncthreads();
    for (int s = 128; s > 0; s >>= 1) {
        if (t < s) red[t] += red[t + s];
        __syncthreads();
    }
    float rsum = 1.f / red[0];

    const int j = t & 63, part = t >> 6;
    float acc = 0.f;
    for (int n = part; n < N_; n += 4)
        acc = fmaf(sc[n], qkv[(long)(b * N_ + n) * QKVLD + 1536 + hh * 64 + j], acc);
    __syncthreads();
    red[t] = acc;
    __syncthreads();
    if (t < 64) {
        float o = (red[t] + red[64 + t] + red[128 + t] + red[192 + t]) * rsum;
        outcat[(long)(b * N_) * C_ + hh * 64 + t] = o;
    }
}

// ---------------------------------------------------------------------------
// Second attention over F=8 + weighted traj sum. Vectorized staging.
// ---------------------------------------------------------------------------
__global__ __launch_bounds__(256)
void attn2_kernel(const float* __restrict__ q2, const ushort_t* __restrict__ k2,
                  const ushort_t* __restrict__ traj, float* __restrict__ outcat,
                  float* __restrict__ attn_out)
{
    const int bs = blockIdx.x;
    const int b = bs / S_, s = bs % S_;
    __shared__ float qs[768];
    __shared__ ushort_t ks[8 * 768];
    __shared__ float logit[12][8];
    __shared__ float wsm[12][8];
    const int t = threadIdx.x;

    // stage q2 row (float4) and k2 rows (uint4 = 8 bf16)
    const float* qrow = q2 + (long)bs * 768;
    if (t < 192) *(float4*)&qs[t * 4] = *(const float4*)(qrow + t * 4);
    const uint4* krow = (const uint4*)(k2 + (long)bs * 6144);
#pragma unroll
    for (int u = t; u < 768; u += 256)
        *(uint4*)&ks[u * 8] = krow[u];
    __syncthreads();

    if (t < 96) {
        int hh = t >> 3, f = t & 7;
        float acc = 0.f;
#pragma unroll 8
        for (int j = 0; j < 64; j++)
            acc = fmaf(qs[hh * 64 + j], bf2f(ks[f * 768 + hh * 64 + j]), acc);
        logit[hh][f] = acc;
    }
    __syncthreads();
    if (t < 12) {
        float m = logit[t][0];
#pragma unroll
        for (int f = 1; f < 8; f++) m = fmaxf(m, logit[t][f]);
        float w[8], sum = 0.f;
#pragma unroll
        for (int f = 0; f < 8; f++) { w[f] = __expf(logit[t][f] - m); sum += w[f]; }
        float r = 1.f / sum;
#pragma unroll
        for (int f = 0; f < 8; f++) wsm[t][f] = w[f] * r;
    }
    __syncthreads();
    if (t < 96) {
        int hh = t >> 3, f = t & 7;
        attn_out[((long)(b * H_ + hh) * S_ + s) * 8 + f] = wsm[hh][f];
    }
    // weighted traj sum: thread t<96 handles 8 contiguous cols, streams traj
    if (t < 96) {
        const int c0 = t * 8, hh = t >> 3;
        const ushort_t* trow = traj + (long)bs * 6144;
        float o[8];
#pragma unroll
        for (int i = 0; i < 8; i++) o[i] = 0.f;
#pragma unroll
        for (int f = 0; f < 8; f++) {
            uint4 tv = *(const uint4*)(trow + f * 768 + c0);
            float wv = wsm[hh][f];
            const ushort_t* e = (const ushort_t*)&tv;
#pragma unroll
            for (int i = 0; i < 8; i++) o[i] = fmaf(wv, bf2f(e[i]), o[i]);
        }
        float* orow = outcat + ((long)(b * N_) + 1 + s) * 768 + c0;
        *(float4*)orow       = make_float4(o[0], o[1], o[2], o[3]);
        *(float4*)(orow + 4) = make_float4(o[4], o[5], o[6], o[7]);
    }
}

// ---------------------------------------------------------------------------
extern "C" void kernel_launch(void* const* d_in, const int* in_sizes, int n_in,
                              void* d_out, int out_size, void* d_ws, size_t ws_size,
                              hipStream_t stream)
{
    (void)in_sizes; (void)n_in; (void)out_size; (void)ws_size;
    const float* x     = (const float*)d_in[0];
    const float* Wqkv  = (const float*)d_in[1];
    const float* Wpq   = (const float*)d_in[2];
    const float* Wpkv  = (const float*)d_in[3];
    const float* Wproj = (const float*)d_in[4];
    const float* bproj = (const float*)d_in[5];
    float* out = (float*)d_out;

    char* p = (char*)d_ws;
    // region A: qkv f32 (28.9 MB), later overwritten by traj_bf (38.5 MB)
    float*    qkv     = (float*)p;
    ushort_t* traj_bf = (ushort_t*)p;
    p += (size_t)25088 * 768 * 2;
    float* q2 = (float*)p;  p += (size_t)3136 * 768 * 4;
    // region C: [x_bf | q_bf | k_bf | vT_bf] early, k2_bf (38.5 MB) late
    char* c0 = p;
    ushort_t* k2_bf = (ushort_t*)c0;
    ushort_t* x_bf  = (ushort_t*)c0;
    ushort_t* q_bf  = (ushort_t*)(c0 + (size_t)4819968);
    ushort_t* k_bf  = (ushort_t*)(c0 + (size_t)4819968 + 4816896);
    ushort_t* vT_bf = (ushort_t*)(c0 + (size_t)4819968 + 4816896 + 5111808);
    p += (size_t)25088 * 768 * 2;
    float*    outcat    = (float*)p;     p += (size_t)3138 * 768 * 4;
    ushort_t* outcat_bf = (ushort_t*)p;  p += (size_t)3138 * 768 * 2;
    ushort_t* Wqkv_t  = (ushort_t*)p;    p += (size_t)1769472 * 2;
    ushort_t* Wpq_t   = (ushort_t*)p;    p += (size_t)589824 * 2;
    ushort_t* Wpkv_t  = (ushort_t*)p;    p += (size_t)589824 * 2;
    ushort_t* Wproj_t = (ushort_t*)p;    p += (size_t)589824 * 2;
    float* attn_out = out + (size_t)3138 * 768;

    // input conversions
    cvt_f32_bf16<<<2354, 256, 0, stream>>>(x, x_bf, 602496);
    transpose_cvt<<<dim3(72, 24), 256, 0, stream>>>(Wqkv,  Wqkv_t,  768, 2304);
    transpose_cvt<<<dim3(24, 24), 256, 0, stream>>>(Wpq,   Wpq_t,   768, 768);
    transpose_cvt<<<dim3(24, 24), 256, 0, stream>>>(Wpkv,  Wpkv_t,  768, 1536);
    transpose_cvt<<<dim3(24, 24), 256, 0, stream>>>(Wproj, Wproj_t, 768, 768);

    // 1. qkv = x @ W_qkv  (fp32 out)
    gemm_bf16<0, 0><<<dim3(25, 18), 256, 0, stream>>>(x_bf, Wqkv_t, qkv, 3138, 2304, 768, 1.f, nullptr);
    // 2. reshape to fragment-major bf16 layouts
    prep_kv<<<dim3(8, 12, 2), 256, 0, stream>>>(qkv, q_bf, k_bf, vT_bf);
    // 3. CLS attention -> outcat row 0 (last reader of fp32 qkv)
    cls_attn<<<24, 256, 0, stream>>>(qkv, outcat);
    // 4. barrier-free MFMA trajectory attention -> traj_bf (overwrites qkv)
    traj_attn_mfma<<<dim3(25, 12, 2), 256, 0, stream>>>(q_bf, k_bf, vT_bf, traj_bf);
    // 5. q2 = (x_diag @ W_pq) * scale
    gemm_bf16<1, 0><<<dim3(25, 6), 256, 0, stream>>>(traj_bf, Wpq_t, q2, 3136, 768, 768, SCALE, nullptr);
    // 6. k2 = traj @ W_pkv[:, :768] -> bf16 (overwrites x/q/k/vT buffers)
    gemm_bf16<0, 1><<<dim3(196, 6), 256, 0, stream>>>(traj_bf, Wpkv_t, k2_bf, 25088, 768, 768, 1.f, nullptr);
    // 7. F-attention + weighted traj sum
    attn2_kernel<<<3136, 256, 0, stream>>>(q2, k2_bf, traj_bf, outcat, attn_out);
    // 8. out = outcat @ W_proj + b_proj
    cvt_f32_bf16<<<2354, 256, 0, stream>>>(outcat, outcat_bf, 602496);
    gemm_bf16<0, 0><<<dim3(25, 6), 256, 0, stream>>>(outcat_bf, Wproj_t, out, 3138, 768, 768, 1.f, bproj);
}

// Round 5
// 343.253 us; speedup vs baseline: 4.1184x; 1.2742x over previous
//
#include <hip/hip_runtime.h>

#define B_ 2
#define N_ 1569
#define C_ 768
#define H_ 12
#define D_ 64
#define P_ 196
#define F_ 8
#define S_ 1568
#define QKVLD 2304
#define SCALE 0.125f

typedef unsigned short ushort_t;
using short8 = __attribute__((ext_vector_type(8))) short;
using f32x4  = __attribute__((ext_vector_type(4))) float;

__device__ __forceinline__ ushort_t f2bf(float x) {
    unsigned u = __float_as_uint(x);
    u += 0x7fffu + ((u >> 16) & 1);       // RNE
    return (ushort_t)(u >> 16);
}
__device__ __forceinline__ float bf2f(ushort_t h) {
    return __uint_as_float((unsigned)h << 16);
}
__device__ __forceinline__ uint2 pack4(float a, float b, float c, float d) {
    uint2 o;
    o.x = f2bf(a) | ((unsigned)f2bf(b) << 16);
    o.y = f2bf(c) | ((unsigned)f2bf(d) << 16);
    return o;
}

// ---------------------------------------------------------------------------
// fp32 -> bf16 elementwise convert (n4 = n/4 float4 groups)
// ---------------------------------------------------------------------------
__global__ __launch_bounds__(256)
void cvt_f32_bf16(const float* __restrict__ s, ushort_t* __restrict__ d, int n4)
{
    int i = blockIdx.x * 256 + threadIdx.x;
    if (i < n4) {
        float4 v = ((const float4*)s)[i];
        ((uint2*)d)[i] = pack4(v.x, v.y, v.z, v.w);
    }
}

// ---------------------------------------------------------------------------
// Transpose+convert weights: src (K x ldsrc fp32) -> dst (N x K bf16)
// ---------------------------------------------------------------------------
__global__ __launch_bounds__(256)
void transpose_cvt(const float* __restrict__ src, ushort_t* __restrict__ dst,
                   int K, int ldsrc)
{
    __shared__ float tle[32][33];
    const int n0 = blockIdx.x * 32, k0 = blockIdx.y * 32;
    const int tx = threadIdx.x & 31, ty = threadIdx.x >> 5;
#pragma unroll
    for (int j = 0; j < 4; j++)
        tle[ty + 8 * j][tx] = src[(long)(k0 + ty + 8 * j) * ldsrc + n0 + tx];
    __syncthreads();
#pragma unroll
    for (int j = 0; j < 4; j++)
        dst[(long)(n0 + ty + 8 * j) * K + k0 + tx] = f2bf(tle[tx][ty + 8 * j]);
}

// ---------------------------------------------------------------------------
// bf16 MFMA GEMM (verified r2/r3): C = alpha*A@Bt^T (+bias)
// ---------------------------------------------------------------------------
template<int GATHER, int OUTBF>
__global__ __launch_bounds__(256)
void gemm_bf16(const ushort_t* __restrict__ A, const ushort_t* __restrict__ Bt,
               void* __restrict__ Cv, int M, int Nn, int K,
               float alpha, const float* __restrict__ bias)
{
    __shared__ ushort_t As[128][32];
    __shared__ ushort_t Bs[128][32];

    const int tid = threadIdx.x;
    const int m0 = blockIdx.x * 128, n0 = blockIdx.y * 128;
    const int wave = tid >> 6, lane = tid & 63;
    const int wm = (wave & 1) * 64, wn = (wave >> 1) * 64;
    const int lrow = lane & 15, quad = lane >> 4;

    const int srow = tid >> 2, sseg = tid & 3;
    int ma0 = m0 + srow;      if (ma0 >= M) ma0 = M - 1;
    int ma1 = m0 + 64 + srow; if (ma1 >= M) ma1 = M - 1;
    long ra0, ra1;
    if (GATHER) {
        ra0 = (long)ma0 * F_ + (ma0 % S_) / P_;
        ra1 = (long)ma1 * F_ + (ma1 % S_) / P_;
    } else { ra0 = ma0; ra1 = ma1; }
    const ushort_t* ap0 = A + ra0 * K + sseg * 8;
    const ushort_t* ap1 = A + ra1 * K + sseg * 8;
    const ushort_t* bp0 = Bt + (long)(n0 + srow) * K + sseg * 8;
    const ushort_t* bp1 = Bt + (long)(n0 + 64 + srow) * K + sseg * 8;

    f32x4 acc[4][4];
#pragma unroll
    for (int i = 0; i < 4; i++)
#pragma unroll
        for (int j = 0; j < 4; j++) acc[i][j] = (f32x4){0.f, 0.f, 0.f, 0.f};

    uint4 aV0 = *(const uint4*)ap0;
    uint4 aV1 = *(const uint4*)ap1;
    uint4 bV0 = *(const uint4*)bp0;
    uint4 bV1 = *(const uint4*)bp1;

    const int nk = K >> 5;
    for (int kt = 0; kt < nk; kt++) {
        __syncthreads();
        *(uint4*)&As[srow][sseg * 8]      = aV0;
        *(uint4*)&As[64 + srow][sseg * 8] = aV1;
        *(uint4*)&Bs[srow][sseg * 8]      = bV0;
        *(uint4*)&Bs[64 + srow][sseg * 8] = bV1;
        __syncthreads();
        if (kt + 1 < nk) {
            int k0 = (kt + 1) * 32;
            aV0 = *(const uint4*)(ap0 + k0);
            aV1 = *(const uint4*)(ap1 + k0);
            bV0 = *(const uint4*)(bp0 + k0);
            bV1 = *(const uint4*)(bp1 + k0);
        }
        short8 af[4], bf[4];
#pragma unroll
        for (int mt = 0; mt < 4; mt++)
            af[mt] = *(const short8*)&As[wm + mt * 16 + lrow][quad * 8];
#pragma unroll
        for (int nt = 0; nt < 4; nt++)
            bf[nt] = *(const short8*)&Bs[wn + nt * 16 + lrow][quad * 8];
#pragma unroll
        for (int mt = 0; mt < 4; mt++)
#pragma unroll
            for (int nt = 0; nt < 4; nt++)
                acc[mt][nt] = __builtin_amdgcn_mfma_f32_16x16x32_bf16(
                    af[mt], bf[nt], acc[mt][nt], 0, 0, 0);
    }

#pragma unroll
    for (int mt = 0; mt < 4; mt++) {
#pragma unroll
        for (int nt = 0; nt < 4; nt++) {
            int row = m0 + wm + mt * 16 + quad * 4;
            int col = n0 + wn + nt * 16 + lrow;
            float bv = bias ? bias[col] : 0.f;
#pragma unroll
            for (int r = 0; r < 4; r++) {
                if (row + r < M) {
                    float v = acc[mt][nt][r] * alpha + bv;
                    if (OUTBF)
                        ((ushort_t*)Cv)[(long)(row + r) * Nn + col] = f2bf(v);
                    else
                        ((float*)Cv)[(long)(row + r) * Nn + col] = v;
                }
            }
        }
    }
}

// ---------------------------------------------------------------------------
// Pre-pass: qkv fp32 -> fragment-major bf16 layouts for barrier-free attn.
// ---------------------------------------------------------------------------
__global__ __launch_bounds__(256)
void prep_kv(const float* __restrict__ qkv, ushort_t* __restrict__ q_bf,
             ushort_t* __restrict__ k_bf, ushort_t* __restrict__ vT_bf)
{
    const int f = blockIdx.x, h = blockIdx.y, b = blockIdx.z;
    const int t = threadIdx.x;
    const long rowbase = (long)(b * N_ + 1 + f * P_) * QKVLD;

    {
        ushort_t* qd = q_bf + ((long)(b * H_ + h) * S_ + f * P_) * 64;
        for (int u = t; u < P_ * 16; u += 256) {
            int row = u >> 4, seg = u & 15;
            float4 v = *(const float4*)(qkv + rowbase + (long)row * QKVLD + h * 64 + seg * 4);
            *(uint2*)(qd + (long)row * 64 + seg * 4) = pack4(v.x, v.y, v.z, v.w);
        }
    }
    {
        ushort_t* kd = k_bf + (long)((b * H_ + h) * F_ + f) * 13312;
        for (int u = t; u < 208 * 16; u += 256) {
            int key = u >> 4, seg = u & 15;
            float4 v = make_float4(0.f, 0.f, 0.f, 0.f);
            if (key < P_)
                v = *(const float4*)(qkv + rowbase + (long)key * QKVLD + 768 + h * 64 + seg * 4);
            int ks = seg >> 3, qq = (seg >> 1) & 3, j0 = (seg & 1) * 4;
            int nt = key >> 4, lr = key & 15;
            *(uint2*)(kd + ((ks * 13 + nt) * 64 + qq * 16 + lr) * 8 + j0)
                = pack4(v.x, v.y, v.z, v.w);
        }
    }
    __shared__ float Vl[224][68];
    for (int u = t; u < 224 * 16; u += 256) {
        int key = u >> 4, seg = u & 15;
        float4 v = make_float4(0.f, 0.f, 0.f, 0.f);
        if (key < P_)
            v = *(const float4*)(qkv + rowbase + (long)key * QKVLD + 1536 + h * 64 + seg * 4);
        *(float4*)&Vl[key][seg * 4] = v;
    }
    __syncthreads();
    {
        ushort_t* vd = vT_bf + (long)((b * H_ + h) * F_ + f) * 14336;
        for (int u = t; u < 64 * 56; u += 256) {
            int d = u / 56, kb = u % 56;
            int s = kb >> 3, qq = (kb >> 1) & 3, j0 = (kb & 1) * 4;
            int nt = d >> 4, lr = d & 15;
            *(uint2*)(vd + ((s * 4 + nt) * 64 + qq * 16 + lr) * 8 + j0) =
                pack4(Vl[kb*4+0][d], Vl[kb*4+1][d], Vl[kb*4+2][d], Vl[kb*4+3][d]);
        }
    }
}

// ---------------------------------------------------------------------------
// Barrier-free MFMA trajectory attention (verified r4).
// ---------------------------------------------------------------------------
__global__ __launch_bounds__(256)
void traj_attn_mfma(const ushort_t* __restrict__ q_bf,
                    const ushort_t* __restrict__ k_bf,
                    const ushort_t* __restrict__ vT_bf,
                    ushort_t* __restrict__ traj)
{
    __shared__ __align__(16) ushort_t Pl[4][7 * 512];

    const int t = threadIdx.x;
    const int wave = t >> 6, lane = t & 63;
    const int lrow = lane & 15, quad = lane >> 4;
    const int qt = blockIdx.x, h = blockIdx.y, b = blockIdx.z;
    const int s0 = qt * 64;
    const bool v12 = (lrow < 4);

    int qrow = s0 + wave * 16 + lrow; if (qrow > S_ - 1) qrow = S_ - 1;
    const ushort_t* qp = q_bf + ((long)(b * H_ + h) * S_ + qrow) * 64 + quad * 8;
    short8 a0 = *(const short8*)qp;
    short8 a1 = *(const short8*)(qp + 32);

    *(uint2*)&Pl[wave][6 * 512 + 256 + lane * 4] = (uint2){0, 0};

    const ushort_t* kfb = k_bf  + (long)((b * H_ + h) * F_) * 13312;
    const ushort_t* vfb = vT_bf + (long)((b * H_ + h) * F_) * 14336;

#pragma unroll 1
    for (int f = 0; f < F_; f++) {
        const ushort_t* kf = kfb + (long)f * 13312;
        const ushort_t* vf = vfb + (long)f * 14336;

        f32x4 acc[13];
#pragma unroll
        for (int nt = 0; nt < 13; nt++) acc[nt] = (f32x4){0.f, 0.f, 0.f, 0.f};
#pragma unroll
        for (int nt = 0; nt < 13; nt++) {
            short8 bv = *(const short8*)(kf + (long)nt * 512 + lane * 8);
            acc[nt] = __builtin_amdgcn_mfma_f32_16x16x32_bf16(a0, bv, acc[nt], 0, 0, 0);
        }
#pragma unroll
        for (int nt = 0; nt < 13; nt++) {
            short8 bv = *(const short8*)(kf + (long)(13 + nt) * 512 + lane * 8);
            acc[nt] = __builtin_amdgcn_mfma_f32_16x16x32_bf16(a1, bv, acc[nt], 0, 0, 0);
        }

        float rl[4];
#pragma unroll
        for (int r = 0; r < 4; r++) {
            float mx = acc[0][r];
#pragma unroll
            for (int nt = 1; nt < 12; nt++) mx = fmaxf(mx, acc[nt][r]);
            if (v12) mx = fmaxf(mx, acc[12][r]);
#pragma unroll
            for (int off = 1; off < 16; off <<= 1)
                mx = fmaxf(mx, __shfl_xor(mx, off, 16));
            float sum = 0.f;
#pragma unroll
            for (int nt = 0; nt < 12; nt++) {
                float w = __expf((acc[nt][r] - mx) * SCALE);
                acc[nt][r] = w; sum += w;
            }
            {
                float w = v12 ? __expf((acc[12][r] - mx) * SCALE) : 0.f;
                acc[12][r] = w; sum += w;
            }
#pragma unroll
            for (int off = 1; off < 16; off <<= 1)
                sum += __shfl_xor(sum, off, 16);
            rl[r] = 1.f / sum;
        }

#pragma unroll
        for (int nt = 0; nt < 13; nt++) {
            int key = nt * 16 + lrow;
            int base = (key >> 5) * 512 + ((key >> 3) & 3) * 128 + (key & 7) + quad * 32;
#pragma unroll
            for (int r = 0; r < 4; r++)
                Pl[wave][base + r * 8] = f2bf(acc[nt][r]);
        }
        asm volatile("s_waitcnt lgkmcnt(0)" ::: "memory");

        f32x4 av[4];
#pragma unroll
        for (int nt = 0; nt < 4; nt++) av[nt] = (f32x4){0.f, 0.f, 0.f, 0.f};
#pragma unroll
        for (int s = 0; s < 7; s++) {
            short8 af = *(const short8*)&Pl[wave][s * 512 + lane * 8];
#pragma unroll
            for (int nt = 0; nt < 4; nt++) {
                short8 bv = *(const short8*)(vf + (long)(s * 4 + nt) * 512 + lane * 8);
                av[nt] = __builtin_amdgcn_mfma_f32_16x16x32_bf16(af, bv, av[nt], 0, 0, 0);
            }
        }

#pragma unroll
        for (int nt = 0; nt < 4; nt++)
#pragma unroll
            for (int r = 0; r < 4; r++) {
                int so = s0 + wave * 16 + quad * 4 + r;
                if (so < S_)
                    traj[((long)(b * S_ + so) * F_ + f) * C_ + h * 64 + nt * 16 + lrow]
                        = f2bf(av[nt][r] * rl[r]);
            }
    }
}

// ---------------------------------------------------------------------------
// CLS attention, split-K flash-style.
// Part A: grid (13 chunks, 12 h, 2 b); chunk = 128 keys. Writes per-chunk
// (m, l, o[64]) partials (66 floats, stride 68).
// Part B: 24 blocks x 64 thr merges 13 partials -> outcat row 0.
// ---------------------------------------------------------------------------
#define CLS_CH 13
__global__ __launch_bounds__(256)
void cls_attn_part(const float* __restrict__ qkv, float* __restrict__ part)
{
    const int c = blockIdx.x, hh = blockIdx.y, b = blockIdx.z;
    const int t = threadIdx.x;
    const int n0 = c * 128;
    const int nk = (N_ - n0 < 128) ? (N_ - n0) : 128;

    __shared__ float qs[64];
    __shared__ float sc[128];
    __shared__ float red[256];

    if (t < 64) qs[t] = qkv[(long)(b * N_) * QKVLD + hh * 64 + t];
    __syncthreads();

    if (t < 128) {
        float acc = -1e30f;
        if (t < nk) {
            const float* krow = qkv + (long)(b * N_ + n0 + t) * QKVLD + 768 + hh * 64;
            acc = 0.f;
#pragma unroll
            for (int j4 = 0; j4 < 16; j4++) {
                float4 kv = *(const float4*)(krow + j4 * 4);
                acc = fmaf(kv.x, qs[j4*4+0], acc);
                acc = fmaf(kv.y, qs[j4*4+1], acc);
                acc = fmaf(kv.z, qs[j4*4+2], acc);
                acc = fmaf(kv.w, qs[j4*4+3], acc);
            }
            acc *= SCALE;
        }
        sc[t] = acc;
        red[t] = acc;
    }
    __syncthreads();
    for (int s = 64; s > 0; s >>= 1) {
        if (t < s && t + s < 128) red[t] = fmaxf(red[t], red[t + s]);
        __syncthreads();
    }
    const float m = red[0];
    __syncthreads();

    if (t < 128) {
        float w = (t < nk) ? __expf(sc[t] - m) : 0.f;
        sc[t] = w;
        red[t] = w;
    }
    __syncthreads();
    for (int s = 64; s > 0; s >>= 1) {
        if (t < s && t + s < 128) red[t] += red[t + s];
        __syncthreads();
    }
    const float lsum = red[0];
    __syncthreads();

    // o[j] = sum_n sc[n] * V[n][j]; 4 partial groups over keys
    const int j = t & 63, grp = t >> 6;
    float acc = 0.f;
    for (int n = grp; n < nk; n += 4)
        acc = fmaf(sc[n], qkv[(long)(b * N_ + n0 + n) * QKVLD + 1536 + hh * 64 + j], acc);
    red[t] = acc;
    __syncthreads();

    float* pp = part + (long)(((b * H_ + hh) * CLS_CH) + c) * 68;
    if (t < 64)
        pp[2 + t] = red[t] + red[64 + t] + red[128 + t] + red[192 + t];
    if (t == 0) { pp[0] = m; pp[1] = lsum; }
}

__global__ __launch_bounds__(64)
void cls_attn_merge(const float* __restrict__ part, float* __restrict__ outcat)
{
    const int bh = blockIdx.x;
    const int b = bh / H_, hh = bh % H_;
    const int t = threadIdx.x;
    const float* pp = part + (long)(bh * CLS_CH) * 68;

    float m = -1e30f;
#pragma unroll
    for (int c = 0; c < CLS_CH; c++) m = fmaxf(m, pp[c * 68]);
    float l = 0.f, o = 0.f;
#pragma unroll
    for (int c = 0; c < CLS_CH; c++) {
        float w = __expf(pp[c * 68] - m);
        l = fmaf(pp[c * 68 + 1], w, l);
        o = fmaf(pp[c * 68 + 2 + t], w, o);
    }
    outcat[(long)(b * N_) * C_ + hh * 64 + t] = o / l;
}

// ---------------------------------------------------------------------------
// Second attention over F=8 + weighted traj sum (verified r4).
// ---------------------------------------------------------------------------
__global__ __launch_bounds__(256)
void attn2_kernel(const float* __restrict__ q2, const ushort_t* __restrict__ k2,
                  const ushort_t* __restrict__ traj, float* __restrict__ outcat,
                  float* __restrict__ attn_out)
{
    const int bs = blockIdx.x;
    const int b = bs / S_, s = bs % S_;
    __shared__ float qs[768];
    __shared__ ushort_t ks[8 * 768];
    __shared__ float logit[12][8];
    __shared__ float wsm[12][8];
    const int t = threadIdx.x;

    const float* qrow = q2 + (long)bs * 768;
    if (t < 192) *(float4*)&qs[t * 4] = *(const float4*)(qrow + t * 4);
    const uint4* krow = (const uint4*)(k2 + (long)bs * 6144);
#pragma unroll
    for (int u = t; u < 768; u += 256)
        *(uint4*)&ks[u * 8] = krow[u];
    __syncthreads();

    if (t < 96) {
        int hh = t >> 3, f = t & 7;
        float acc = 0.f;
#pragma unroll 8
        for (int j = 0; j < 64; j++)
            acc = fmaf(qs[hh * 64 + j], bf2f(ks[f * 768 + hh * 64 + j]), acc);
        logit[hh][f] = acc;
    }
    __syncthreads();
    if (t < 12) {
        float m = logit[t][0];
#pragma unroll
        for (int f = 1; f < 8; f++) m = fmaxf(m, logit[t][f]);
        float w[8], sum = 0.f;
#pragma unroll
        for (int f = 0; f < 8; f++) { w[f] = __expf(logit[t][f] - m); sum += w[f]; }
        float r = 1.f / sum;
#pragma unroll
        for (int f = 0; f < 8; f++) wsm[t][f] = w[f] * r;
    }
    __syncthreads();
    if (t < 96) {
        int hh = t >> 3, f = t & 7;
        attn_out[((long)(b * H_ + hh) * S_ + s) * 8 + f] = wsm[hh][f];
    }
    if (t < 96) {
        const int c0 = t * 8, hh = t >> 3;
        const ushort_t* trow = traj + (long)bs * 6144;
        float o[8];
#pragma unroll
        for (int i = 0; i < 8; i++) o[i] = 0.f;
#pragma unroll
        for (int f = 0; f < 8; f++) {
            uint4 tv = *(const uint4*)(trow + f * 768 + c0);
            float wv = wsm[hh][f];
            const ushort_t* e = (const ushort_t*)&tv;
#pragma unroll
            for (int i = 0; i < 8; i++) o[i] = fmaf(wv, bf2f(e[i]), o[i]);
        }
        float* orow = outcat + ((long)(b * N_) + 1 + s) * 768 + c0;
        *(float4*)orow       = make_float4(o[0], o[1], o[2], o[3]);
        *(float4*)(orow + 4) = make_float4(o[4], o[5], o[6], o[7]);
    }
}

// ---------------------------------------------------------------------------
extern "C" void kernel_launch(void* const* d_in, const int* in_sizes, int n_in,
                              void* d_out, int out_size, void* d_ws, size_t ws_size,
                              hipStream_t stream)
{
    (void)in_sizes; (void)n_in; (void)out_size; (void)ws_size;
    const float* x     = (const float*)d_in[0];
    const float* Wqkv  = (const float*)d_in[1];
    const float* Wpq   = (const float*)d_in[2];
    const float* Wpkv  = (const float*)d_in[3];
    const float* Wproj = (const float*)d_in[4];
    const float* bproj = (const float*)d_in[5];
    float* out = (float*)d_out;

    char* p = (char*)d_ws;
    // region A: qkv f32 (28.9 MB), later overwritten by traj_bf (38.5 MB)
    float*    qkv     = (float*)p;
    ushort_t* traj_bf = (ushort_t*)p;
    p += (size_t)25088 * 768 * 2;
    float* q2 = (float*)p;  p += (size_t)3136 * 768 * 4;
    // region C: [x_bf | q_bf | k_bf | vT_bf] early, k2_bf (38.5 MB) late
    char* c0 = p;
    ushort_t* k2_bf = (ushort_t*)c0;
    ushort_t* x_bf  = (ushort_t*)c0;
    ushort_t* q_bf  = (ushort_t*)(c0 + (size_t)4819968);
    ushort_t* k_bf  = (ushort_t*)(c0 + (size_t)4819968 + 4816896);
    ushort_t* vT_bf = (ushort_t*)(c0 + (size_t)4819968 + 4816896 + 5111808);
    p += (size_t)25088 * 768 * 2;
    float*    outcat    = (float*)p;     p += (size_t)3138 * 768 * 4;
    ushort_t* outcat_bf = (ushort_t*)p;  p += (size_t)3138 * 768 * 2;
    ushort_t* Wqkv_t  = (ushort_t*)p;    p += (size_t)1769472 * 2;
    ushort_t* Wpq_t   = (ushort_t*)p;    p += (size_t)589824 * 2;
    ushort_t* Wpkv_t  = (ushort_t*)p;    p += (size_t)589824 * 2;
    ushort_t* Wproj_t = (ushort_t*)p;    p += (size_t)589824 * 2;
    float*    cls_part = (float*)p;      p += (size_t)24 * CLS_CH * 68 * 4;
    float* attn_out = out + (size_t)3138 * 768;

    // input conversions
    cvt_f32_bf16<<<2354, 256, 0, stream>>>(x, x_bf, 602496);
    transpose_cvt<<<dim3(72, 24), 256, 0, stream>>>(Wqkv,  Wqkv_t,  768, 2304);
    transpose_cvt<<<dim3(24, 24), 256, 0, stream>>>(Wpq,   Wpq_t,   768, 768);
    transpose_cvt<<<dim3(24, 24), 256, 0, stream>>>(Wpkv,  Wpkv_t,  768, 1536);
    transpose_cvt<<<dim3(24, 24), 256, 0, stream>>>(Wproj, Wproj_t, 768, 768);

    // 1. qkv = x @ W_qkv  (fp32 out)
    gemm_bf16<0, 0><<<dim3(25, 18), 256, 0, stream>>>(x_bf, Wqkv_t, qkv, 3138, 2304, 768, 1.f, nullptr);
    // 2. reshape to fragment-major bf16 layouts
    prep_kv<<<dim3(8, 12, 2), 256, 0, stream>>>(qkv, q_bf, k_bf, vT_bf);
    // 3. CLS attention (split-K) -> outcat row 0 (last reader of fp32 qkv)
    cls_attn_part<<<dim3(CLS_CH, 12, 2), 256, 0, stream>>>(qkv, cls_part);
    cls_attn_merge<<<24, 64, 0, stream>>>(cls_part, outcat);
    // 4. barrier-free MFMA trajectory attention -> traj_bf (overwrites qkv)
    traj_attn_mfma<<<dim3(25, 12, 2), 256, 0, stream>>>(q_bf, k_bf, vT_bf, traj_bf);
    // 5. q2 = (x_diag @ W_pq) * scale
    gemm_bf16<1, 0><<<dim3(25, 6), 256, 0, stream>>>(traj_bf, Wpq_t, q2, 3136, 768, 768, SCALE, nullptr);
    // 6. k2 = traj @ W_pkv[:, :768] -> bf16 (overwrites x/q/k/vT buffers)
    gemm_bf16<0, 1><<<dim3(196, 6), 256, 0, stream>>>(traj_bf, Wpkv_t, k2_bf, 25088, 768, 768, 1.f, nullptr);
    // 7. F-attention + weighted traj sum
    attn2_kernel<<<3136, 256, 0, stream>>>(q2, k2_bf, traj_bf, outcat, attn_out);
    // 8. out = outcat @ W_proj + b_proj
    cvt_f32_bf16<<<2354, 256, 0, stream>>>(outcat, outcat_bf, 602496);
    gemm_bf16<0, 0><<<dim3(25, 6), 256, 0, stream>>>(outcat_bf, Wproj_t, out, 3138, 768, 768, 1.f, bproj);
}